// Round 8
// baseline (618.766 us; speedup 1.0000x reference)
//
#include <hip/hip_runtime.h>
#include <math.h>

#define B_    2
#define S_    2048
#define E_    2048
#define H_    32
#define HKV_  8
#define D_    64

typedef __bf16 bf16x8 __attribute__((ext_vector_type(8)));
typedef float  f32x4  __attribute__((ext_vector_type(4)));
typedef float  f32x16 __attribute__((ext_vector_type(16)));
typedef unsigned int u32x2 __attribute__((ext_vector_type(2)));
typedef unsigned int u32x4 __attribute__((ext_vector_type(4)));

#define GPTR(x) ((const __attribute__((address_space(1))) void*)(x))
#define LPTR(x) ((__attribute__((address_space(3))) void*)(x))

// 0.125 * log2(e): folded into Q so attention softmax is exp2-direct.
#define QK_SCALE_LOG2E 0.18033688011112042f

// ---------------------------------------------------------------------------
// fp32 -> bf16 flat convert (x)
// ---------------------------------------------------------------------------
__global__ __launch_bounds__(256) void convert_kernel(
    const float* __restrict__ in, __bf16* __restrict__ out, int n8)
{
    const int i = blockIdx.x * 256 + threadIdx.x;
    if (i >= n8) return;
    const float4 a = ((const float4*)in)[i * 2];
    const float4 b = ((const float4*)in)[i * 2 + 1];
    bf16x8 o;
    o[0] = (__bf16)a.x; o[1] = (__bf16)a.y; o[2] = (__bf16)a.z; o[3] = (__bf16)a.w;
    o[4] = (__bf16)b.x; o[5] = (__bf16)b.y; o[6] = (__bf16)b.z; o[7] = (__bf16)b.w;
    ((bf16x8*)out)[i] = o;
}

// ---------------------------------------------------------------------------
// All 4 weight transposes (fp32 (K,N) -> bf16 (N,K)) in ONE dispatch.
// ---------------------------------------------------------------------------
__global__ __launch_bounds__(256) void transpose_convert_all_kernel(
    const float* __restrict__ wq, const float* __restrict__ wk,
    const float* __restrict__ wv, const float* __restrict__ wo,
    __bf16* __restrict__ wT, __bf16* __restrict__ woT)
{
    const float* in; __bf16* out; int N, xb;
    const int x = blockIdx.x;
    if (x < 64)      { in = wq; out = wT;                        N = 2048; xb = x; }
    else if (x < 80) { in = wk; out = wT + (size_t)2048 * 2048;  N = 512;  xb = x - 64; }
    else if (x < 96) { in = wv; out = wT + (size_t)2560 * 2048;  N = 512;  xb = x - 80; }
    else             { in = wo; out = woT;                       N = 2048; xb = x - 96; }
    const int K = 2048;

    __shared__ float tile[32][33];
    const int k0 = blockIdx.y * 32, n0 = xb * 32;
    const int r  = threadIdx.x >> 3;
    const int c4 = (threadIdx.x & 7) * 4;
    const float4 v = *(const float4*)&in[(size_t)(k0 + r) * N + n0 + c4];
    tile[r][c4 + 0] = v.x; tile[r][c4 + 1] = v.y;
    tile[r][c4 + 2] = v.z; tile[r][c4 + 3] = v.w;
    __syncthreads();
    ushort4 o;
    __bf16 h0 = (__bf16)tile[c4 + 0][r]; o.x = __builtin_bit_cast(unsigned short, h0);
    __bf16 h1 = (__bf16)tile[c4 + 1][r]; o.y = __builtin_bit_cast(unsigned short, h1);
    __bf16 h2 = (__bf16)tile[c4 + 2][r]; o.z = __builtin_bit_cast(unsigned short, h2);
    __bf16 h3 = (__bf16)tile[c4 + 3][r]; o.w = __builtin_bit_cast(unsigned short, h3);
    *(ushort4*)&out[(size_t)(n0 + r) * K + k0 + c4] = o;
}

// ---------------------------------------------------------------------------
// Pipelined GEMM (unchanged from R5: 4-slot ring, counted vmcnt).
// ---------------------------------------------------------------------------
template<int BN> struct PG {
    static constexpr int BM     = 256;
    static constexpr int BK     = 32;
    static constexpr int ASLOT  = BM * BK;
    static constexpr int BSLOT  = BN * BK;
    static constexpr int SLOT   = ASLOT + BSLOT;
    static constexpr int BINSTR = BN / 128;
    static constexpr int L      = 2 + BINSTR;
    static constexpr int NJ     = BN / 64;
};

template<int BN>
__device__ __forceinline__ void stage_tile(
    const __bf16* __restrict__ A, const __bf16* __restrict__ Bt,
    int m0, int n0, int K, int T, __bf16* sl, int t, int wbase)
{
    using G = PG<BN>;
    const int k0   = T * G::BK;
    const int rsub = t >> 2;
    const int cp   = t & 3;
#pragma unroll
    for (int g = 0; g < 2; ++g) {
        const int row = g * 128 + rsub;
        const int cl  = cp ^ ((row >> 1) & 3);
        __builtin_amdgcn_global_load_lds(
            GPTR(A + (size_t)(m0 + row) * K + k0 + cl * 8),
            LPTR(sl + (g * 512 + wbase) * 8), 16, 0, 0);
    }
#pragma unroll
    for (int g = 0; g < G::BINSTR; ++g) {
        const int row = g * 128 + rsub;
        const int cl  = cp ^ ((row >> 1) & 3);
        __builtin_amdgcn_global_load_lds(
            GPTR(Bt + (size_t)(n0 + row) * K + k0 + cl * 8),
            LPTR(sl + G::ASLOT + (g * 512 + wbase) * 8), 16, 0, 0);
    }
}

template<int BN>
__device__ __forceinline__ void compute_tile(
    const __bf16* sl, int wrow, int wcol, int col, int quad,
    f32x4 acc[8][PG<BN>::NJ])
{
    using G = PG<BN>;
    bf16x8 af[8], bfr[G::NJ];
#pragma unroll
    for (int i = 0; i < 8; ++i) {
        const int m = wrow + i * 16 + col;
        af[i] = *(const bf16x8*)&sl[m * 32 + ((quad ^ ((m >> 1) & 3)) * 8)];
    }
#pragma unroll
    for (int j = 0; j < G::NJ; ++j) {
        const int n = wcol + j * 16 + col;
        bfr[j] = *(const bf16x8*)&sl[G::ASLOT + n * 32 + ((quad ^ ((n >> 1) & 3)) * 8)];
    }
    __builtin_amdgcn_s_setprio(1);
#pragma unroll
    for (int i = 0; i < 8; ++i)
#pragma unroll
        for (int j = 0; j < G::NJ; ++j)
            acc[i][j] = __builtin_amdgcn_mfma_f32_16x16x32_bf16(
                af[i], bfr[j], acc[i][j], 0, 0, 0);
    __builtin_amdgcn_s_setprio(0);
}

template<int BN>
__device__ __forceinline__ void gemm_pipe_body(
    const __bf16* __restrict__ A, const __bf16* __restrict__ Bt,
    int m0, int n0, int K, __bf16* sL, f32x4 acc[8][PG<BN>::NJ])
{
    using G = PG<BN>;
    const int t     = threadIdx.x;
    const int wbase = t & ~63;
    const int lane  = t & 63;
    const int col   = lane & 15;
    const int quad  = lane >> 4;
    const int w     = t >> 6;
    const int wrow  = (w >> 2) * 128;
    const int wcol  = (w & 3) * (BN / 4);
    const int NT    = K / G::BK;

    stage_tile<BN>(A, Bt, m0, n0, K, 0, sL + 0 * G::SLOT, t, wbase);
    stage_tile<BN>(A, Bt, m0, n0, K, 1, sL + 1 * G::SLOT, t, wbase);
    stage_tile<BN>(A, Bt, m0, n0, K, 2, sL + 2 * G::SLOT, t, wbase);

    int T = 0;
#pragma unroll 1
    for (; T < NT - 3; ++T) {
        asm volatile("s_waitcnt vmcnt(%0)" :: "n"(2 * G::L) : "memory");
        __builtin_amdgcn_s_barrier();
        stage_tile<BN>(A, Bt, m0, n0, K, T + 3, sL + ((T + 3) & 3) * G::SLOT, t, wbase);
        compute_tile<BN>(sL + (T & 3) * G::SLOT, wrow, wcol, col, quad, acc);
    }
    asm volatile("s_waitcnt vmcnt(%0)" :: "n"(2 * G::L) : "memory");
    __builtin_amdgcn_s_barrier();
    compute_tile<BN>(sL + (T & 3) * G::SLOT, wrow, wcol, col, quad, acc); ++T;
    asm volatile("s_waitcnt vmcnt(%0)" :: "n"(G::L) : "memory");
    __builtin_amdgcn_s_barrier();
    compute_tile<BN>(sL + (T & 3) * G::SLOT, wrow, wcol, col, quad, acc); ++T;
    asm volatile("s_waitcnt vmcnt(0)" ::: "memory");
    __builtin_amdgcn_s_barrier();
    compute_tile<BN>(sL + (T & 3) * G::SLOT, wrow, wcol, col, quad, acc);
}

// ---------------------------------------------------------------------------
// QKV GEMM (BM=256, BN=256): 192 blocks, fused RoPE/scale epilogue.
// ---------------------------------------------------------------------------
__global__ __launch_bounds__(512, 2) void gemm_qkv_kernel(
    const __bf16* __restrict__ xb, const __bf16* __restrict__ wT,
    const float* __restrict__ fc, const float* __restrict__ fs,
    __bf16* __restrict__ qb, __bf16* __restrict__ kb, __bf16* __restrict__ vb)
{
    __shared__ __bf16 sL[4 * PG<256>::SLOT];   // 128 KiB
    f32x4 acc[8][4];
#pragma unroll
    for (int i = 0; i < 8; ++i)
#pragma unroll
        for (int j = 0; j < 4; ++j) acc[i][j] = (f32x4){0.f, 0.f, 0.f, 0.f};

    const int lin     = blockIdx.x;
    const int logical = (lin & 7) * 24 + (lin >> 3);
    const int bx      = logical % 12;
    const int m0      = (logical / 12) * 256;
    const int n0      = bx * 256;

    gemm_pipe_body<256>(xb, wT, m0, n0, E_, sL, acc);

    __bf16* Cp; int ldc, base;
    if (bx < 8)       { Cp = qb; ldc = H_ * D_;   base = 0;    }
    else if (bx < 10) { Cp = kb; ldc = HKV_ * D_; base = 2048; }
    else              { Cp = vb; ldc = HKV_ * D_; base = 2560; }
    const bool  doRope = (bx < 10);
    const float qsc    = (bx < 8) ? QK_SCALE_LOG2E : 1.0f;

    const int t    = threadIdx.x;
    const int lane = t & 63;
    const int col  = lane & 15;
    const int quad = lane >> 4;
    const int w    = t >> 6;
    const int wrow = (w >> 2) * 128;
    const int wcol = (w & 3) * 64;
#pragma unroll
    for (int i = 0; i < 8; ++i)
#pragma unroll
        for (int j = 0; j < 4; ++j)
#pragma unroll
            for (int r = 0; r < 4; ++r) {
                const int m  = m0 + wrow + i * 16 + quad * 4 + r;
                const int ng = n0 + wcol + j * 16 + col;
                float val = acc[i][j][r] * qsc;
                if (doRope) {
                    const int   s    = m & (S_ - 1);
                    const int   pair = (ng & 63) >> 1;
                    const float c    = fc[s * 32 + pair];
                    const float sn   = fs[s * 32 + pair];
                    const float oth  = __shfl_xor(val, 1);
                    val = (lane & 1) ? (oth * sn + val * c)
                                     : (val * c - oth * sn);
                }
                Cp[(size_t)m * ldc + (ng - base)] = (__bf16)val;
            }
}

// ---------------------------------------------------------------------------
// Output GEMM (BM=256, BN=128): 256 blocks, bias epilogue.
// ---------------------------------------------------------------------------
__global__ __launch_bounds__(512, 2) void gemm_out_kernel(
    const __bf16* __restrict__ ob, const __bf16* __restrict__ woT,
    const float* __restrict__ bias, float* __restrict__ out)
{
    __shared__ __bf16 sL[4 * PG<128>::SLOT];   // 96 KiB
    f32x4 acc[8][2];
#pragma unroll
    for (int i = 0; i < 8; ++i)
#pragma unroll
        for (int j = 0; j < 2; ++j) acc[i][j] = (f32x4){0.f, 0.f, 0.f, 0.f};

    const int lin     = blockIdx.x;
    const int logical = (lin & 7) * 32 + (lin >> 3);
    const int n0      = (logical % 16) * 128;
    const int m0      = (logical / 16) * 256;

    gemm_pipe_body<128>(ob, woT, m0, n0, H_ * D_, sL, acc);

    const int t    = threadIdx.x;
    const int lane = t & 63;
    const int col  = lane & 15;
    const int quad = lane >> 4;
    const int w    = t >> 6;
    const int wrow = (w >> 2) * 128;
    const int wcol = (w & 3) * 32;
#pragma unroll
    for (int i = 0; i < 8; ++i)
#pragma unroll
        for (int j = 0; j < 2; ++j)
#pragma unroll
            for (int r = 0; r < 4; ++r) {
                const int m = m0 + wrow + i * 16 + quad * 4 + r;
                const int n = n0 + wcol + j * 16 + col;
                out[(size_t)m * E_ + n] = acc[i][j][r] + bias[n];
            }
}

// ---------------------------------------------------------------------------
// MFMA flash attention v6: K read DIRECTLY from global (L2); V-only LDS.
// R6/R7 analysis: LDS pipe was ~6x oversubscribed vs MFMA (16 ds_read_b128
// + staging writes per wave-tile, all 4 waves reading IDENTICAL fragments;
// amortizing over more q hits a register wall -> R7 spilled 245 MB).
// The aK fragment is a per-lane CONTIGUOUS 16B read (K[key][8 dims]) -- the
// same shape as the LDS read -- so K comes straight from global instead:
// kills sK staging loads + ds_writes + ds_reads => LDS traffic halves,
// LDS 36.9 -> 18.4 KB. A bijective KV-grouped XCD swizzle puts exactly 2
// KV-groups (1 MB K+V) on each XCD's 4MB L2 -> K reads are L2 hits.
// __launch_bounds__(256,4): cap 128 vs measured demand 116 (R6) -> fits.
// Spill tripwire: WRITE_SIZE must stay 16384 (R3/R7 lessons).
// ---------------------------------------------------------------------------
struct StageRegs {
    ushort4 va0, vc0, va1, vc1;
};

__device__ __forceinline__ void stage_load(
    StageRegs& r, const __bf16* vbase, int j0, int vkp, int vdg)
{
    const int KSTR = HKV_ * D_;   // 512
    const __bf16* v0 = vbase + (size_t)(j0 + vkp) * KSTR + vdg;
    r.va0 = *(const ushort4*)(v0);
    r.vc0 = *(const ushort4*)(v0 + KSTR);
    r.va1 = *(const ushort4*)(v0 + 32);
    r.vc1 = *(const ushort4*)(v0 + KSTR + 32);
}

__device__ __forceinline__ void stage_write(
    const StageRegs& r, __bf16 (*sVT)[72], int vkp, int vdg)
{
    *(unsigned int*)&sVT[vdg + 0][vkp]      = ((unsigned)r.vc0.x << 16) | r.va0.x;
    *(unsigned int*)&sVT[vdg + 1][vkp]      = ((unsigned)r.vc0.y << 16) | r.va0.y;
    *(unsigned int*)&sVT[vdg + 2][vkp]      = ((unsigned)r.vc0.z << 16) | r.va0.z;
    *(unsigned int*)&sVT[vdg + 3][vkp]      = ((unsigned)r.vc0.w << 16) | r.va0.w;
    *(unsigned int*)&sVT[vdg + 32 + 0][vkp] = ((unsigned)r.vc1.x << 16) | r.va1.x;
    *(unsigned int*)&sVT[vdg + 32 + 1][vkp] = ((unsigned)r.vc1.y << 16) | r.va1.y;
    *(unsigned int*)&sVT[vdg + 32 + 2][vkp] = ((unsigned)r.vc1.z << 16) | r.va1.z;
    *(unsigned int*)&sVT[vdg + 32 + 3][vkp] = ((unsigned)r.vc1.w << 16) | r.va1.w;
}

__device__ __forceinline__ bf16x8 pack_pa(const f32x16& p, int i0)
{
    unsigned a0, a1, a2, a3;
    asm("v_cvt_pk_bf16_f32 %0, %1, %2" : "=v"(a0) : "v"(p[i0 + 0]), "v"(p[i0 + 1]));
    asm("v_cvt_pk_bf16_f32 %0, %1, %2" : "=v"(a1) : "v"(p[i0 + 2]), "v"(p[i0 + 3]));
    asm("v_cvt_pk_bf16_f32 %0, %1, %2" : "=v"(a2) : "v"(p[i0 + 4]), "v"(p[i0 + 5]));
    asm("v_cvt_pk_bf16_f32 %0, %1, %2" : "=v"(a3) : "v"(p[i0 + 6]), "v"(p[i0 + 7]));
    const u32x2 s02 = __builtin_amdgcn_permlane32_swap(a0, a2, false, false);
    const u32x2 s13 = __builtin_amdgcn_permlane32_swap(a1, a3, false, false);
    return __builtin_bit_cast(bf16x8, (u32x4){s02[0], s13[0], s02[1], s13[1]});
}

// kp0/kp1: this lane's K row pointers (rows j0+lq and j0+32+lq, dim offset
// hi*8 pre-applied). aK fragments load as contiguous bf16x8 from global/L2.
__device__ __forceinline__ void attn_tile(
    const __bf16* kp0, const __bf16* kp1, const __bf16 (*sVT)[72],
    const bf16x8* bQ, int lq, int hi,
    f32x16& O0, f32x16& O1, float& lsum)
{
    // --- QK^T: two independent accumulation chains (keys 0-31 / 32-63)
    f32x16 p0, p1;
#pragma unroll
    for (int i = 0; i < 16; ++i) { p0[i] = 0.f; p1[i] = 0.f; }
    __builtin_amdgcn_s_setprio(1);
#pragma unroll
    for (int ks = 0; ks < 4; ++ks) {
        const bf16x8 aK0 = *(const bf16x8*)(kp0 + ks * 16);
        const bf16x8 aK1 = *(const bf16x8*)(kp1 + ks * 16);
        p0 = __builtin_amdgcn_mfma_f32_32x32x16_bf16(aK0, bQ[ks], p0, 0, 0, 0);
        p1 = __builtin_amdgcn_mfma_f32_32x32x16_bf16(aK1, bQ[ks], p1, 0, 0, 0);
    }
    __builtin_amdgcn_s_setprio(0);

    // --- issue V fragment reads early: latency hides under softmax VALU
    bf16x8 vbf[8];
#pragma unroll
    for (int ks = 0; ks < 4; ++ks) {
        vbf[ks * 2]     = *(const bf16x8*)&sVT[lq][ks * 16 + hi * 8];
        vbf[ks * 2 + 1] = *(const bf16x8*)&sVT[32 + lq][ks * 16 + hi * 8];
    }

    // --- softmax: 32 independent exp2, running denominator
    float ps = 0.f;
#pragma unroll
    for (int i = 0; i < 16; ++i) {
        p0[i] = __builtin_amdgcn_exp2f(p0[i]);
        p1[i] = __builtin_amdgcn_exp2f(p1[i]);
        ps += p0[i] + p1[i];
    }
    lsum += ps;

    bf16x8 pa[4];
    pa[0] = pack_pa(p0, 0);
    pa[1] = pack_pa(p0, 8);
    pa[2] = pack_pa(p1, 0);
    pa[3] = pack_pa(p1, 8);

    // --- PV
    __builtin_amdgcn_s_setprio(1);
#pragma unroll
    for (int ks = 0; ks < 4; ++ks) {
        O0 = __builtin_amdgcn_mfma_f32_32x32x16_bf16(pa[ks], vbf[ks * 2],     O0, 0, 0, 0);
        O1 = __builtin_amdgcn_mfma_f32_32x32x16_bf16(pa[ks], vbf[ks * 2 + 1], O1, 0, 0, 0);
    }
    __builtin_amdgcn_s_setprio(0);
}

__global__ __launch_bounds__(256, 4) void attn_kernel(
    const __bf16* __restrict__ qw, const __bf16* __restrict__ kw,
    const __bf16* __restrict__ vw, __bf16* __restrict__ ow)
{
    __shared__ __bf16 sVT0[64][72], sVT1[64][72];   // 18.4 KiB total

    const int t    = threadIdx.x;
    const int lane = t & 63;
    const int w    = t >> 6;
    const int lq   = lane & 31;
    const int hi   = lane >> 5;

    // Bijective KV-grouped XCD swizzle: 1024 blocks; XCD p = wgid&7 owns
    // KV-groups {2p, 2p+1} -> 1 MB K+V working set per XCD L2.
    const int wgid = blockIdx.x;
    const int p    = wgid & 7;
    const int idx  = wgid >> 3;            // 0..127
    const int gkv  = p * 2 + (idx >> 6);   // 0..15 = b*8+kvh
    const int sub  = idx & 63;             // 0..63
    const int hg   = sub >> 4;             // head within kv-group
    const int qx   = sub & 15;             // q-tile
    const int b    = gkv >> 3;
    const int kvh  = gkv & 7;
    const int h    = kvh * 4 + hg;
    const int q0   = qx * 128 + w * 32;

    bf16x8 bQ[4];
    {
        const __bf16* qrow = qw + (((size_t)b * S_ + q0 + lq) * H_ + h) * D_;
#pragma unroll
        for (int ks = 0; ks < 4; ++ks)
            bQ[ks] = *(const bf16x8*)(qrow + ks * 16 + hi * 8);
    }

    f32x16 O0, O1;
#pragma unroll
    for (int i = 0; i < 16; ++i) { O0[i] = 0.f; O1[i] = 0.f; }
    float lsum = 0.f;

    const int KSTR = HKV_ * D_;   // 512
    const __bf16* kbase = kw + ((size_t)b * S_ * HKV_ + kvh) * D_;
    const __bf16* vbase = vw + ((size_t)b * S_ * HKV_ + kvh) * D_;
    // per-lane K row pointers: rows (j0+lq) and (j0+32+lq), dim offset hi*8
    const __bf16* krow0 = kbase + (size_t)lq * KSTR + hi * 8;
    const __bf16* krow1 = krow0 + (size_t)32 * KSTR;

    const int vkp = (t & 31) * 2, vdg = (t >> 5) * 4;

    StageRegs sr;
    stage_load(sr, vbase, 0, vkp, vdg);
    stage_write(sr, sVT0, vkp, vdg);
    __syncthreads();

#pragma unroll 1
    for (int j0 = 0; j0 < S_; j0 += 128) {
        StageRegs nx;
        stage_load(nx, vbase, j0 + 64, vkp, vdg);
        attn_tile(krow0 + (size_t)j0 * KSTR, krow1 + (size_t)j0 * KSTR,
                  sVT0, bQ, lq, hi, O0, O1, lsum);
        stage_write(nx, sVT1, vkp, vdg);
        __syncthreads();
        if (j0 + 128 < S_)
            stage_load(nx, vbase, j0 + 128, vkp, vdg);
        attn_tile(krow0 + (size_t)(j0 + 64) * KSTR, krow1 + (size_t)(j0 + 64) * KSTR,
                  sVT1, bQ, lq, hi, O0, O1, lsum);
        if (j0 + 128 < S_)
            stage_write(nx, sVT0, vkp, vdg);
        __syncthreads();
    }

    // lane and lane^32 hold complementary key-halves of the denominator.
    lsum += __shfl_xor(lsum, 32);
    const float inv = 1.0f / lsum;

    // O C-layout: col = lane&31 = d-in-block, row q = (r&3)+8*(r>>2)+4*hi.
#pragma unroll
    for (int r = 0; r < 16; ++r) {
        const int   qr = (r & 3) + 8 * (r >> 2) + 4 * hi;
        const float li = __shfl(inv, qr);
        __bf16* orow = ow + (((size_t)b * S_ + q0 + qr) * H_ + h) * D_;
        orow[lq]      = (__bf16)(O0[r] * li);
        orow[32 + lq] = (__bf16)(O1[r] * li);
    }
}

// ---------------------------------------------------------------------------
extern "C" void kernel_launch(void* const* d_in, const int* in_sizes, int n_in,
                              void* d_out, int out_size, void* d_ws, size_t ws_size,
                              hipStream_t stream)
{
    const float* x  = (const float*)d_in[0];
    const float* fc = (const float*)d_in[2];
    const float* fs = (const float*)d_in[3];
    const float* wq = (const float*)d_in[4];
    const float* wk = (const float*)d_in[5];
    const float* wv = (const float*)d_in[6];
    const float* wo = (const float*)d_in[7];
    const float* obias = (const float*)d_in[8];
    float* out = (float*)d_out;

    __bf16* ws  = (__bf16*)d_ws;
    __bf16* xb  = ws;                                    // 4096*2048
    __bf16* wT  = xb  + (size_t)4096 * 2048;             // 3072*2048 [wq^T|wk^T|wv^T]
    __bf16* woT = wT  + (size_t)3072 * 2048;             // 2048*2048
    __bf16* qb  = woT + (size_t)2048 * 2048;             // B,S,H,D
    __bf16* kb  = qb  + (size_t)B_ * S_ * H_ * D_;       // B,S,HKV,D
    __bf16* vb  = kb  + (size_t)B_ * S_ * HKV_ * D_;
    __bf16* obf = vb  + (size_t)B_ * S_ * HKV_ * D_;     // B,S,H,D

    convert_kernel<<<4096, 256, 0, stream>>>(x, xb, 4096 * 2048 / 8);
    transpose_convert_all_kernel<<<dim3(160, 64), 256, 0, stream>>>(
        wq, wk, wv, wo, wT, woT);

    gemm_qkv_kernel<<<192, 512, 0, stream>>>(xb, wT, fc, fs, qb, kb, vb);

    attn_kernel<<<1024, 256, 0, stream>>>(qb, kb, vb, obf);

    gemm_out_kernel<<<256, 512, 0, stream>>>(obf, woT, obias, out);
}

// Round 9
// 482.071 us; speedup vs baseline: 1.2836x; 1.2836x over previous
//
#include <hip/hip_runtime.h>
#include <math.h>

#define B_    2
#define S_    2048
#define E_    2048
#define H_    32
#define HKV_  8
#define D_    64

typedef __bf16 bf16x8 __attribute__((ext_vector_type(8)));
typedef float  f32x4  __attribute__((ext_vector_type(4)));
typedef float  f32x16 __attribute__((ext_vector_type(16)));
typedef unsigned int u32x2 __attribute__((ext_vector_type(2)));
typedef unsigned int u32x4 __attribute__((ext_vector_type(4)));

#define GPTR(x) ((const __attribute__((address_space(1))) void*)(x))
#define LPTR(x) ((__attribute__((address_space(3))) void*)(x))

// 0.125 * log2(e): folded into Q so attention softmax is exp2-direct.
#define QK_SCALE_LOG2E 0.18033688011112042f

// ---------------------------------------------------------------------------
// fp32 -> bf16 flat convert (x)
// ---------------------------------------------------------------------------
__global__ __launch_bounds__(256) void convert_kernel(
    const float* __restrict__ in, __bf16* __restrict__ out, int n8)
{
    const int i = blockIdx.x * 256 + threadIdx.x;
    if (i >= n8) return;
    const float4 a = ((const float4*)in)[i * 2];
    const float4 b = ((const float4*)in)[i * 2 + 1];
    bf16x8 o;
    o[0] = (__bf16)a.x; o[1] = (__bf16)a.y; o[2] = (__bf16)a.z; o[3] = (__bf16)a.w;
    o[4] = (__bf16)b.x; o[5] = (__bf16)b.y; o[6] = (__bf16)b.z; o[7] = (__bf16)b.w;
    ((bf16x8*)out)[i] = o;
}

// ---------------------------------------------------------------------------
// All 4 weight transposes (fp32 (K,N) -> bf16 (N,K)) in ONE dispatch.
// ---------------------------------------------------------------------------
__global__ __launch_bounds__(256) void transpose_convert_all_kernel(
    const float* __restrict__ wq, const float* __restrict__ wk,
    const float* __restrict__ wv, const float* __restrict__ wo,
    __bf16* __restrict__ wT, __bf16* __restrict__ woT)
{
    const float* in; __bf16* out; int N, xb;
    const int x = blockIdx.x;
    if (x < 64)      { in = wq; out = wT;                        N = 2048; xb = x; }
    else if (x < 80) { in = wk; out = wT + (size_t)2048 * 2048;  N = 512;  xb = x - 64; }
    else if (x < 96) { in = wv; out = wT + (size_t)2560 * 2048;  N = 512;  xb = x - 80; }
    else             { in = wo; out = woT;                       N = 2048; xb = x - 96; }
    const int K = 2048;

    __shared__ float tile[32][33];
    const int k0 = blockIdx.y * 32, n0 = xb * 32;
    const int r  = threadIdx.x >> 3;
    const int c4 = (threadIdx.x & 7) * 4;
    const float4 v = *(const float4*)&in[(size_t)(k0 + r) * N + n0 + c4];
    tile[r][c4 + 0] = v.x; tile[r][c4 + 1] = v.y;
    tile[r][c4 + 2] = v.z; tile[r][c4 + 3] = v.w;
    __syncthreads();
    ushort4 o;
    __bf16 h0 = (__bf16)tile[c4 + 0][r]; o.x = __builtin_bit_cast(unsigned short, h0);
    __bf16 h1 = (__bf16)tile[c4 + 1][r]; o.y = __builtin_bit_cast(unsigned short, h1);
    __bf16 h2 = (__bf16)tile[c4 + 2][r]; o.z = __builtin_bit_cast(unsigned short, h2);
    __bf16 h3 = (__bf16)tile[c4 + 3][r]; o.w = __builtin_bit_cast(unsigned short, h3);
    *(ushort4*)&out[(size_t)(n0 + r) * K + k0 + c4] = o;
}

// ---------------------------------------------------------------------------
// 8-phase pipelined GEMM (m201 structure): BM=BN=256, BK=64, 512 thr/8 waves
// (2M x 4N). LDS 128 KiB = 2 buf x {A,B} x 2 half-tiles[128][64], st_16x32
// swizzle (elem col ^= 16 if row&4) applied on ds_read + inverse on the
// global source; global_load_lds dest stays linear (base + lane*16B).
// Per iteration: 2 K-tiles (buf0: phases P1-4, buf1: P5-8). Each phase:
//   {ds_read subtile; stage 1 half-tile (2 gload_lds/thread);
//    barrier; lgkmcnt(0); sched_barrier; setprio(1); 16 MFMA; setprio(0);
//    barrier}
// Stage slots (verified free >=1 phase after last cross-wave read, and
// drained by a vmcnt(4)+barrier before next read):
//   P1: b1.Blo[2I+1]  P2: b1.Bhi[2I+1]  P3: b0.Alo[2I+2]  P4: b0.Ahi[2I+2]
//   P5: b0.Blo[2I+2]  P6: b0.Bhi[2I+2]  P7: b1.Alo[2I+3]  P8: b1.Ahi[2I+3]
// vmcnt(4) at END of P4 (drains b1[2I+1]'s 4 HTs) and P8 (drains b0[2I+2]).
// Reads per window: p1: A-h0(8)+B-h0(4) -> quad(m0,n0); p2: A-h1(8) ->
// (m1,n0); p3: B-h1(4) -> (m1,n1); p4: none -> (m0,n1) from kept regs.
// Tail: staged K-tile indices clamped (keeps vmcnt counts constant).
// ---------------------------------------------------------------------------
#define SWZ(row, col) ((row) * 64 + ((col) ^ (((row) & 4) << 2)))

__device__ __forceinline__ __bf16* ht_ptr(__bf16* sL, int c, int mat, int half)
{
    return sL + (((c * 2 + mat) * 2 + half) * (128 * 64));
}

// Stage one 128x64 half-tile: 512 threads x 2 loads x 16B. LDS dest linear
// (base + lane*16B within wave); global source pre-swizzled.
__device__ __forceinline__ void stage_ht(
    const __bf16* __restrict__ src, int ld, int row0, int k0,
    __bf16* dst, int t)
{
#pragma unroll
    for (int g = 0; g < 2; ++g) {
        const int row = g * 64 + (t >> 3);
        const int ch  = (t & 7) ^ ((row & 4) >> 1);   // inverse st_16x32 (16B units)
        __builtin_amdgcn_global_load_lds(
            GPTR(src + (size_t)(row0 + row) * ld + k0 + ch * 8),
            LPTR(dst + row * 64 + (t & 7) * 8), 16, 0, 0);
    }
}

__device__ __forceinline__ void read_a(
    const __bf16* aht, int mh, int col16, int quad, bf16x8 fr[4][2])
{
#pragma unroll
    for (int i = 0; i < 4; ++i) {
        const int r = mh * 64 + i * 16 + col16;
#pragma unroll
        for (int ks = 0; ks < 2; ++ks)
            fr[i][ks] = *(const bf16x8*)&aht[SWZ(r, ks * 32 + quad * 8)];
    }
}

__device__ __forceinline__ void read_b(
    const __bf16* bht, int bofs, int nh, int col16, int quad, bf16x8 fr[2][2])
{
#pragma unroll
    for (int j = 0; j < 2; ++j) {
        const int r = bofs + (nh * 2 + j) * 16 + col16;
#pragma unroll
        for (int ks = 0; ks < 2; ++ks)
            fr[j][ks] = *(const bf16x8*)&bht[SWZ(r, ks * 32 + quad * 8)];
    }
}

__device__ __forceinline__ void mfma_quad(
    const bf16x8 a[4][2], const bf16x8 b[2][2], f32x4 acc[8][4], int mh, int nh)
{
    __builtin_amdgcn_s_setprio(1);
#pragma unroll
    for (int i = 0; i < 4; ++i)
#pragma unroll
        for (int j = 0; j < 2; ++j)
#pragma unroll
            for (int ks = 0; ks < 2; ++ks)
                acc[mh * 4 + i][nh * 2 + j] = __builtin_amdgcn_mfma_f32_16x16x32_bf16(
                    a[i][ks], b[j][ks], acc[mh * 4 + i][nh * 2 + j], 0, 0, 0);
    __builtin_amdgcn_s_setprio(0);
}

#define MIDBAR() do { __builtin_amdgcn_s_barrier(); \
    asm volatile("s_waitcnt lgkmcnt(0)" ::: "memory"); \
    __builtin_amdgcn_sched_barrier(0); } while (0)
#define ENDBAR() __builtin_amdgcn_s_barrier()

__device__ __forceinline__ void gemm8_body(
    const __bf16* __restrict__ A, const __bf16* __restrict__ Bt,
    int m0, int n0, int K, __bf16* sL, f32x4 acc[8][4])
{
    const int t     = threadIdx.x;
    const int lane  = t & 63;
    const int w     = t >> 6;
    const int col16 = lane & 15;
    const int quad  = lane >> 4;
    const int wr    = w >> 2;       // 0,1
    const int wc    = w & 3;        // 0..3
    const int NT    = K / 64;

    // prologue: b0 = tile0 (all 4 HTs), b1 = tile1 (A only)
    stage_ht(A,  K, m0 + 0,   0,  ht_ptr(sL, 0, 0, 0), t);
    stage_ht(A,  K, m0 + 128, 0,  ht_ptr(sL, 0, 0, 1), t);
    stage_ht(Bt, K, n0 + 0,   0,  ht_ptr(sL, 0, 1, 0), t);
    stage_ht(Bt, K, n0 + 128, 0,  ht_ptr(sL, 0, 1, 1), t);
    stage_ht(A,  K, m0 + 0,   64, ht_ptr(sL, 1, 0, 0), t);
    stage_ht(A,  K, m0 + 128, 64, ht_ptr(sL, 1, 0, 1), t);
    asm volatile("s_waitcnt vmcnt(4)" ::: "memory");
    __builtin_amdgcn_s_barrier();

    const __bf16* myA[2] = { ht_ptr(sL, 0, 0, wr),      ht_ptr(sL, 1, 0, wr) };
    const __bf16* myB[2] = { ht_ptr(sL, 0, 1, wc >> 1), ht_ptr(sL, 1, 1, wc >> 1) };
    const int bofs = (wc & 1) * 64;

    bf16x8 a0[4][2], a1[4][2], b0f[2][2], b1f[2][2];

#pragma unroll 1
    for (int I = 0; I < NT / 2; ++I) {
        const int k1  = (2 * I + 1) * 64;
        const int kt2 = (2 * I + 2 < NT) ? 2 * I + 2 : NT - 1;
        const int kt3 = (2 * I + 3 < NT) ? 2 * I + 3 : NT - 1;

        // ---- window 0: tile 2I (buf0) ----
        read_a(myA[0], 0, col16, quad, a0);
        read_b(myB[0], bofs, 0, col16, quad, b0f);
        stage_ht(Bt, K, n0 + 0, k1, ht_ptr(sL, 1, 1, 0), t);        // P1
        MIDBAR(); mfma_quad(a0, b0f, acc, 0, 0); ENDBAR();

        read_a(myA[0], 1, col16, quad, a1);
        stage_ht(Bt, K, n0 + 128, k1, ht_ptr(sL, 1, 1, 1), t);      // P2
        MIDBAR(); mfma_quad(a1, b0f, acc, 1, 0); ENDBAR();

        read_b(myB[0], bofs, 1, col16, quad, b1f);
        stage_ht(A, K, m0 + 0, kt2 * 64, ht_ptr(sL, 0, 0, 0), t);   // P3
        MIDBAR(); mfma_quad(a1, b1f, acc, 1, 1); ENDBAR();

        stage_ht(A, K, m0 + 128, kt2 * 64, ht_ptr(sL, 0, 0, 1), t); // P4
        asm volatile("s_waitcnt vmcnt(4)" ::: "memory");
        MIDBAR(); mfma_quad(a0, b1f, acc, 0, 1); ENDBAR();

        // ---- window 1: tile 2I+1 (buf1) ----
        read_a(myA[1], 0, col16, quad, a0);
        read_b(myB[1], bofs, 0, col16, quad, b0f);
        stage_ht(Bt, K, n0 + 0, kt2 * 64, ht_ptr(sL, 0, 1, 0), t);  // P5
        MIDBAR(); mfma_quad(a0, b0f, acc, 0, 0); ENDBAR();

        read_a(myA[1], 1, col16, quad, a1);
        stage_ht(Bt, K, n0 + 128, kt2 * 64, ht_ptr(sL, 0, 1, 1), t);// P6
        MIDBAR(); mfma_quad(a1, b0f, acc, 1, 0); ENDBAR();

        read_b(myB[1], bofs, 1, col16, quad, b1f);
        stage_ht(A, K, m0 + 0, kt3 * 64, ht_ptr(sL, 1, 0, 0), t);   // P7
        MIDBAR(); mfma_quad(a1, b1f, acc, 1, 1); ENDBAR();

        stage_ht(A, K, m0 + 128, kt3 * 64, ht_ptr(sL, 1, 0, 1), t); // P8
        asm volatile("s_waitcnt vmcnt(4)" ::: "memory");
        MIDBAR(); mfma_quad(a0, b1f, acc, 0, 1); ENDBAR();
    }
}

// ---------------------------------------------------------------------------
// QKV GEMM: M=4096, N=3072 (Q|K|V), K=2048. 16x12 = 192 blocks.
// Fused RoPE/scale epilogue (proven R3-R6).
// ---------------------------------------------------------------------------
__global__ __launch_bounds__(512, 2) void gemm_qkv_kernel(
    const __bf16* __restrict__ xb, const __bf16* __restrict__ wT,
    const float* __restrict__ fc, const float* __restrict__ fs,
    __bf16* __restrict__ qb, __bf16* __restrict__ kb, __bf16* __restrict__ vb)
{
    __shared__ __bf16 sL[8 * 128 * 64];   // 128 KiB
    f32x4 acc[8][4];
#pragma unroll
    for (int i = 0; i < 8; ++i)
#pragma unroll
        for (int j = 0; j < 4; ++j) acc[i][j] = (f32x4){0.f, 0.f, 0.f, 0.f};

    // T1: bijective XCD swizzle over 192 blocks.
    const int lin     = blockIdx.x;
    const int logical = (lin & 7) * 24 + (lin >> 3);
    const int bx      = logical % 12;          // 0-7 Q, 8-9 K, 10-11 V
    const int m0      = (logical / 12) * 256;
    const int n0      = bx * 256;

    gemm8_body(xb, wT, m0, n0, E_, sL, acc);

    __bf16* Cp; int ldc, base;
    if (bx < 8)       { Cp = qb; ldc = H_ * D_;   base = 0;    }
    else if (bx < 10) { Cp = kb; ldc = HKV_ * D_; base = 2048; }
    else              { Cp = vb; ldc = HKV_ * D_; base = 2560; }
    const bool  doRope = (bx < 10);
    const float qsc    = (bx < 8) ? QK_SCALE_LOG2E : 1.0f;

    const int t     = threadIdx.x;
    const int lane  = t & 63;
    const int col16 = lane & 15;
    const int quad  = lane >> 4;
    const int w     = t >> 6;
    const int wrow  = (w >> 2) * 128;
    const int wcol  = (w & 3) * 64;
#pragma unroll
    for (int i = 0; i < 8; ++i)
#pragma unroll
        for (int j = 0; j < 4; ++j)
#pragma unroll
            for (int r = 0; r < 4; ++r) {
                const int m  = m0 + wrow + i * 16 + quad * 4 + r;
                const int ng = n0 + wcol + j * 16 + col16;
                float val = acc[i][j][r] * qsc;
                if (doRope) {
                    const int   s    = m & (S_ - 1);
                    const int   pair = (ng & 63) >> 1;
                    const float c    = fc[s * 32 + pair];
                    const float sn   = fs[s * 32 + pair];
                    const float oth  = __shfl_xor(val, 1);
                    val = (lane & 1) ? (oth * sn + val * c)
                                     : (val * c - oth * sn);
                }
                Cp[(size_t)m * ldc + (ng - base)] = (__bf16)val;
            }
}

// ---------------------------------------------------------------------------
// Output GEMM: M=4096, N=2048, K=2048. 16x8 = 128 blocks. Bias epilogue.
// ---------------------------------------------------------------------------
__global__ __launch_bounds__(512, 2) void gemm_out_kernel(
    const __bf16* __restrict__ ob, const __bf16* __restrict__ woT,
    const float* __restrict__ bias, float* __restrict__ out)
{
    __shared__ __bf16 sL[8 * 128 * 64];   // 128 KiB
    f32x4 acc[8][4];
#pragma unroll
    for (int i = 0; i < 8; ++i)
#pragma unroll
        for (int j = 0; j < 4; ++j) acc[i][j] = (f32x4){0.f, 0.f, 0.f, 0.f};

    // T1: bijective XCD swizzle over 128 blocks.
    const int lin     = blockIdx.x;
    const int logical = (lin & 7) * 16 + (lin >> 3);
    const int n0      = (logical % 8) * 256;
    const int m0      = (logical / 8) * 256;

    gemm8_body(ob, woT, m0, n0, H_ * D_, sL, acc);

    const int t     = threadIdx.x;
    const int lane  = t & 63;
    const int col16 = lane & 15;
    const int quad  = lane >> 4;
    const int w     = t >> 6;
    const int wrow  = (w >> 2) * 128;
    const int wcol  = (w & 3) * 64;
#pragma unroll
    for (int i = 0; i < 8; ++i)
#pragma unroll
        for (int j = 0; j < 4; ++j)
#pragma unroll
            for (int r = 0; r < 4; ++r) {
                const int m = m0 + wrow + i * 16 + quad * 4 + r;
                const int n = n0 + wcol + j * 16 + col16;
                out[(size_t)m * E_ + n] = acc[i][j][r] + bias[n];
            }
}

// ---------------------------------------------------------------------------
// MFMA flash attention (R6 body verbatim: 112 µs, 116 VGPR, no spill).
// Dual-chain QK^T; V reads hoisted; exp2-direct; cvt_pk+permlane pack.
// __launch_bounds__(256) ONLY — (256,3) caps at 84 VGPR (ok, R4=110µs) but
// (256,4) and the 64q variant spill 245-650 MB (R3/R7/R8). Total demand
// ~180 VGPR+AGPR -> 2 waves/SIMD is this body's ceiling. Do not force.
// ---------------------------------------------------------------------------
struct StageRegs {
    bf16x8  k0, k1;
    ushort4 va0, vc0, va1, vc1;
};

__device__ __forceinline__ void stage_load(
    StageRegs& r, const __bf16* kbase, const __bf16* vbase, int j0,
    int kkey, int kd, int vkp, int vdg)
{
    const int KSTR = HKV_ * D_;   // 512
    const __bf16* kr = kbase + (size_t)(j0 + kkey) * KSTR + kd;
    r.k0 = ((const bf16x8*)kr)[0];
    r.k1 = ((const bf16x8*)kr)[1];
    const __bf16* v0 = vbase + (size_t)(j0 + vkp) * KSTR + vdg;
    r.va0 = *(const ushort4*)(v0);
    r.vc0 = *(const ushort4*)(v0 + KSTR);
    r.va1 = *(const ushort4*)(v0 + 32);
    r.vc1 = *(const ushort4*)(v0 + KSTR + 32);
}

__device__ __forceinline__ void stage_write(
    const StageRegs& r, __bf16 (*sK)[72], __bf16 (*sVT)[72],
    int kkey, int kd, int vkp, int vdg)
{
    *(bf16x8*)&sK[kkey][kd]     = r.k0;
    *(bf16x8*)&sK[kkey][kd + 8] = r.k1;
    *(unsigned int*)&sVT[vdg + 0][vkp]      = ((unsigned)r.vc0.x << 16) | r.va0.x;
    *(unsigned int*)&sVT[vdg + 1][vkp]      = ((unsigned)r.vc0.y << 16) | r.va0.y;
    *(unsigned int*)&sVT[vdg + 2][vkp]      = ((unsigned)r.vc0.z << 16) | r.va0.z;
    *(unsigned int*)&sVT[vdg + 3][vkp]      = ((unsigned)r.vc0.w << 16) | r.va0.w;
    *(unsigned int*)&sVT[vdg + 32 + 0][vkp] = ((unsigned)r.vc1.x << 16) | r.va1.x;
    *(unsigned int*)&sVT[vdg + 32 + 1][vkp] = ((unsigned)r.vc1.y << 16) | r.va1.y;
    *(unsigned int*)&sVT[vdg + 32 + 2][vkp] = ((unsigned)r.vc1.z << 16) | r.va1.z;
    *(unsigned int*)&sVT[vdg + 32 + 3][vkp] = ((unsigned)r.vc1.w << 16) | r.va1.w;
}

__device__ __forceinline__ bf16x8 pack_pa(const f32x16& p, int i0)
{
    unsigned a0, a1, a2, a3;
    asm("v_cvt_pk_bf16_f32 %0, %1, %2" : "=v"(a0) : "v"(p[i0 + 0]), "v"(p[i0 + 1]));
    asm("v_cvt_pk_bf16_f32 %0, %1, %2" : "=v"(a1) : "v"(p[i0 + 2]), "v"(p[i0 + 3]));
    asm("v_cvt_pk_bf16_f32 %0, %1, %2" : "=v"(a2) : "v"(p[i0 + 4]), "v"(p[i0 + 5]));
    asm("v_cvt_pk_bf16_f32 %0, %1, %2" : "=v"(a3) : "v"(p[i0 + 6]), "v"(p[i0 + 7]));
    const u32x2 s02 = __builtin_amdgcn_permlane32_swap(a0, a2, false, false);
    const u32x2 s13 = __builtin_amdgcn_permlane32_swap(a1, a3, false, false);
    return __builtin_bit_cast(bf16x8, (u32x4){s02[0], s13[0], s02[1], s13[1]});
}

__device__ __forceinline__ void attn_tile(
    const __bf16 (*sK)[72], const __bf16 (*sVT)[72],
    const bf16x8* bQ, int lq, int hi,
    f32x16& O0, f32x16& O1, float& lsum)
{
    f32x16 p0, p1;
#pragma unroll
    for (int i = 0; i < 16; ++i) { p0[i] = 0.f; p1[i] = 0.f; }
    __builtin_amdgcn_s_setprio(1);
#pragma unroll
    for (int ks = 0; ks < 4; ++ks) {
        const bf16x8 aK0 = *(const bf16x8*)&sK[lq][ks * 16 + hi * 8];
        const bf16x8 aK1 = *(const bf16x8*)&sK[32 + lq][ks * 16 + hi * 8];
        p0 = __builtin_amdgcn_mfma_f32_32x32x16_bf16(aK0, bQ[ks], p0, 0, 0, 0);
        p1 = __builtin_amdgcn_mfma_f32_32x32x16_bf16(aK1, bQ[ks], p1, 0, 0, 0);
    }
    __builtin_amdgcn_s_setprio(0);

    bf16x8 vbf[8];
#pragma unroll
    for (int ks = 0; ks < 4; ++ks) {
        vbf[ks * 2]     = *(const bf16x8*)&sVT[lq][ks * 16 + hi * 8];
        vbf[ks * 2 + 1] = *(const bf16x8*)&sVT[32 + lq][ks * 16 + hi * 8];
    }

    float ps = 0.f;
#pragma unroll
    for (int i = 0; i < 16; ++i) {
        p0[i] = __builtin_amdgcn_exp2f(p0[i]);
        p1[i] = __builtin_amdgcn_exp2f(p1[i]);
        ps += p0[i] + p1[i];
    }
    lsum += ps;

    bf16x8 pa[4];
    pa[0] = pack_pa(p0, 0);
    pa[1] = pack_pa(p0, 8);
    pa[2] = pack_pa(p1, 0);
    pa[3] = pack_pa(p1, 8);

    __builtin_amdgcn_s_setprio(1);
#pragma unroll
    for (int ks = 0; ks < 4; ++ks) {
        O0 = __builtin_amdgcn_mfma_f32_32x32x16_bf16(pa[ks], vbf[ks * 2],     O0, 0, 0, 0);
        O1 = __builtin_amdgcn_mfma_f32_32x32x16_bf16(pa[ks], vbf[ks * 2 + 1], O1, 0, 0, 0);
    }
    __builtin_amdgcn_s_setprio(0);
}

__global__ __launch_bounds__(256) void attn_kernel(
    const __bf16* __restrict__ qw, const __bf16* __restrict__ kw,
    const __bf16* __restrict__ vw, __bf16* __restrict__ ow)
{
    __shared__ __bf16 sK0[64][72], sVT0[64][72];
    __shared__ __bf16 sK1[64][72], sVT1[64][72];

    const int t    = threadIdx.x;
    const int lane = t & 63;
    const int w    = t >> 6;
    const int lq   = lane & 31;
    const int hi   = lane >> 5;

    const int bh  = blockIdx.y;
    const int b   = bh >> 5;
    const int h   = bh & 31;
    const int kvh = h >> 2;
    const int q0  = blockIdx.x * 128 + w * 32;

    bf16x8 bQ[4];
    {
        const __bf16* qrow = qw + (((size_t)b * S_ + q0 + lq) * H_ + h) * D_;
#pragma unroll
        for (int ks = 0; ks < 4; ++ks)
            bQ[ks] = *(const bf16x8*)(qrow + ks * 16 + hi * 8);
    }

    f32x16 O0, O1;
#pragma unroll
    for (int i = 0; i < 16; ++i) { O0[i] = 0.f; O1[i] = 0.f; }
    float lsum = 0.f;

    const __bf16* kbase = kw + ((size_t)b * S_ * HKV_ + kvh) * D_;
    const __bf16* vbase = vw + ((size_t)b * S_ * HKV_ + kvh) * D_;
    const int kkey = t >> 2,        kd  = (t & 3) * 16;
    const int vkp  = (t & 31) * 2,  vdg = (t >> 5) * 4;

    StageRegs sr;
    stage_load(sr, kbase, vbase, 0, kkey, kd, vkp, vdg);
    stage_write(sr, sK0, sVT0, kkey, kd, vkp, vdg);
    __syncthreads();

#pragma unroll 1
    for (int j0 = 0; j0 < S_; j0 += 128) {
        StageRegs nx;
        stage_load(nx, kbase, vbase, j0 + 64, kkey, kd, vkp, vdg);
        attn_tile(sK0, sVT0, bQ, lq, hi, O0, O1, lsum);
        stage_write(nx, sK1, sVT1, kkey, kd, vkp, vdg);
        __syncthreads();
        if (j0 + 128 < S_)
            stage_load(nx, kbase, vbase, j0 + 128, kkey, kd, vkp, vdg);
        attn_tile(sK1, sVT1, bQ, lq, hi, O0, O1, lsum);
        if (j0 + 128 < S_)
            stage_write(nx, sK0, sVT0, kkey, kd, vkp, vdg);
        __syncthreads();
    }

    lsum += __shfl_xor(lsum, 32);
    const float inv = 1.0f / lsum;

#pragma unroll
    for (int r = 0; r < 16; ++r) {
        const int   qr = (r & 3) + 8 * (r >> 2) + 4 * hi;
        const float li = __shfl(inv, qr);
        __bf16* orow = ow + (((size_t)b * S_ + q0 + qr) * H_ + h) * D_;
        orow[lq]      = (__bf16)(O0[r] * li);
        orow[32 + lq] = (__bf16)(O1[r] * li);
    }
}

// ---------------------------------------------------------------------------
extern "C" void kernel_launch(void* const* d_in, const int* in_sizes, int n_in,
                              void* d_out, int out_size, void* d_ws, size_t ws_size,
                              hipStream_t stream)
{
    const float* x  = (const float*)d_in[0];
    const float* fc = (const float*)d_in[2];
    const float* fs = (const float*)d_in[3];
    const float* wq = (const float*)d_in[4];
    const float* wk = (const float*)d_in[5];
    const float* wv = (const float*)d_in[6];
    const float* wo = (const float*)d_in[7];
    const float* obias = (const float*)d_in[8];
    float* out = (float*)d_out;

    __bf16* ws  = (__bf16*)d_ws;
    __bf16* xb  = ws;                                    // 4096*2048
    __bf16* wT  = xb  + (size_t)4096 * 2048;             // 3072*2048 [wq^T|wk^T|wv^T]
    __bf16* woT = wT  + (size_t)3072 * 2048;             // 2048*2048
    __bf16* qb  = woT + (size_t)2048 * 2048;             // B,S,H,D
    __bf16* kb  = qb  + (size_t)B_ * S_ * H_ * D_;       // B,S,HKV,D
    __bf16* vb  = kb  + (size_t)B_ * S_ * HKV_ * D_;
    __bf16* obf = vb  + (size_t)B_ * S_ * HKV_ * D_;     // B,S,H,D

    convert_kernel<<<4096, 256, 0, stream>>>(x, xb, 4096 * 2048 / 8);
    transpose_convert_all_kernel<<<dim3(160, 64), 256, 0, stream>>>(
        wq, wk, wv, wo, wT, woT);

    gemm_qkv_kernel<<<192, 512, 0, stream>>>(xb, wT, fc, fs, qb, kb, vb);

    attn_kernel<<<dim3(S_ / 128, B_ * H_), 256, 0, stream>>>(qb, kb, vb, obf);

    gemm_out_kernel<<<128, 512, 0, stream>>>(obf, woT, obias, out);
}

// Round 10
// 361.535 us; speedup vs baseline: 1.7115x; 1.3334x over previous
//
#include <hip/hip_runtime.h>
#include <math.h>

#define B_    2
#define S_    2048
#define E_    2048
#define H_    32
#define HKV_  8
#define D_    64

typedef __bf16 bf16x8 __attribute__((ext_vector_type(8)));
typedef float  f32x4  __attribute__((ext_vector_type(4)));
typedef float  f32x16 __attribute__((ext_vector_type(16)));
typedef unsigned int u32x2 __attribute__((ext_vector_type(2)));
typedef unsigned int u32x4 __attribute__((ext_vector_type(4)));

#define GPTR(x) ((const __attribute__((address_space(1))) void*)(x))
#define LPTR(x) ((__attribute__((address_space(3))) void*)(x))

// 0.125 * log2(e): folded into Q so attention softmax is exp2-direct.
#define QK_SCALE_LOG2E 0.18033688011112042f

// ---------------------------------------------------------------------------
// fp32 -> bf16 flat convert (x)
// ---------------------------------------------------------------------------
__global__ __launch_bounds__(256) void convert_kernel(
    const float* __restrict__ in, __bf16* __restrict__ out, int n8)
{
    const int i = blockIdx.x * 256 + threadIdx.x;
    if (i >= n8) return;
    const float4 a = ((const float4*)in)[i * 2];
    const float4 b = ((const float4*)in)[i * 2 + 1];
    bf16x8 o;
    o[0] = (__bf16)a.x; o[1] = (__bf16)a.y; o[2] = (__bf16)a.z; o[3] = (__bf16)a.w;
    o[4] = (__bf16)b.x; o[5] = (__bf16)b.y; o[6] = (__bf16)b.z; o[7] = (__bf16)b.w;
    ((bf16x8*)out)[i] = o;
}

// ---------------------------------------------------------------------------
// All 4 weight transposes (fp32 (K,N) -> bf16 (N,K)) in ONE dispatch.
// ---------------------------------------------------------------------------
__global__ __launch_bounds__(256) void transpose_convert_all_kernel(
    const float* __restrict__ wq, const float* __restrict__ wk,
    const float* __restrict__ wv, const float* __restrict__ wo,
    __bf16* __restrict__ wT, __bf16* __restrict__ woT)
{
    const float* in; __bf16* out; int N, xb;
    const int x = blockIdx.x;
    if (x < 64)      { in = wq; out = wT;                        N = 2048; xb = x; }
    else if (x < 80) { in = wk; out = wT + (size_t)2048 * 2048;  N = 512;  xb = x - 64; }
    else if (x < 96) { in = wv; out = wT + (size_t)2560 * 2048;  N = 512;  xb = x - 80; }
    else             { in = wo; out = woT;                       N = 2048; xb = x - 96; }
    const int K = 2048;

    __shared__ float tile[32][33];
    const int k0 = blockIdx.y * 32, n0 = xb * 32;
    const int r  = threadIdx.x >> 3;
    const int c4 = (threadIdx.x & 7) * 4;
    const float4 v = *(const float4*)&in[(size_t)(k0 + r) * N + n0 + c4];
    tile[r][c4 + 0] = v.x; tile[r][c4 + 1] = v.y;
    tile[r][c4 + 2] = v.z; tile[r][c4 + 3] = v.w;
    __syncthreads();
    ushort4 o;
    __bf16 h0 = (__bf16)tile[c4 + 0][r]; o.x = __builtin_bit_cast(unsigned short, h0);
    __bf16 h1 = (__bf16)tile[c4 + 1][r]; o.y = __builtin_bit_cast(unsigned short, h1);
    __bf16 h2 = (__bf16)tile[c4 + 2][r]; o.z = __builtin_bit_cast(unsigned short, h2);
    __bf16 h3 = (__bf16)tile[c4 + 3][r]; o.w = __builtin_bit_cast(unsigned short, h3);
    *(ushort4*)&out[(size_t)(n0 + r) * K + k0 + c4] = o;
}

// ---------------------------------------------------------------------------
// Pipelined ring GEMM (R5 structure, generalized BM): 512 thr = 8 waves
// (2M x 4N), BK=32, 4-slot LDS ring, counted vmcnt (never 0 in main loop).
// Proven good (R5/R6). R9's 8-phase port regressed to 315 TF (operand-reg
// spill + barrier overload + swizzle conflicts) -- reverted.
// ---------------------------------------------------------------------------
template<int BM, int BN> struct PG {
    static constexpr int BK     = 32;
    static constexpr int ASLOT  = BM * BK;
    static constexpr int BSLOT  = BN * BK;
    static constexpr int SLOT   = ASLOT + BSLOT;
    static constexpr int AINSTR = BM / 128;      // gload instrs for A per tile
    static constexpr int BINSTR = BN / 128;
    static constexpr int L      = AINSTR + BINSTR;
    static constexpr int MI     = BM / 32;       // A-frags per wave (rows/16)
    static constexpr int NJ     = BN / 64;       // B-frags per wave
};

template<int BM, int BN>
__device__ __forceinline__ void stage_tile(
    const __bf16* __restrict__ A, const __bf16* __restrict__ Bt,
    int m0, int n0, int K, int T, __bf16* sl, int t, int wbase)
{
    using G = PG<BM, BN>;
    const int k0   = T * G::BK;
    const int rsub = t >> 2;
    const int cp   = t & 3;
#pragma unroll
    for (int g = 0; g < G::AINSTR; ++g) {
        const int row = g * 128 + rsub;
        const int cl  = cp ^ ((row >> 1) & 3);
        __builtin_amdgcn_global_load_lds(
            GPTR(A + (size_t)(m0 + row) * K + k0 + cl * 8),
            LPTR(sl + (g * 512 + wbase) * 8), 16, 0, 0);
    }
#pragma unroll
    for (int g = 0; g < G::BINSTR; ++g) {
        const int row = g * 128 + rsub;
        const int cl  = cp ^ ((row >> 1) & 3);
        __builtin_amdgcn_global_load_lds(
            GPTR(Bt + (size_t)(n0 + row) * K + k0 + cl * 8),
            LPTR(sl + G::ASLOT + (g * 512 + wbase) * 8), 16, 0, 0);
    }
}

template<int BM, int BN>
__device__ __forceinline__ void compute_tile(
    const __bf16* sl, int wrow, int wcol, int col, int quad,
    f32x4 acc[PG<BM, BN>::MI][PG<BM, BN>::NJ])
{
    using G = PG<BM, BN>;
    bf16x8 af[G::MI], bfr[G::NJ];
#pragma unroll
    for (int i = 0; i < G::MI; ++i) {
        const int m = wrow + i * 16 + col;
        af[i] = *(const bf16x8*)&sl[m * 32 + ((quad ^ ((m >> 1) & 3)) * 8)];
    }
#pragma unroll
    for (int j = 0; j < G::NJ; ++j) {
        const int n = wcol + j * 16 + col;
        bfr[j] = *(const bf16x8*)&sl[G::ASLOT + n * 32 + ((quad ^ ((n >> 1) & 3)) * 8)];
    }
    __builtin_amdgcn_s_setprio(1);
#pragma unroll
    for (int i = 0; i < G::MI; ++i)
#pragma unroll
        for (int j = 0; j < G::NJ; ++j)
            acc[i][j] = __builtin_amdgcn_mfma_f32_16x16x32_bf16(
                af[i], bfr[j], acc[i][j], 0, 0, 0);
    __builtin_amdgcn_s_setprio(0);
}

template<int BM, int BN>
__device__ __forceinline__ void gemm_pipe_body(
    const __bf16* __restrict__ A, const __bf16* __restrict__ Bt,
    int m0, int n0, int K, __bf16* sL,
    f32x4 acc[PG<BM, BN>::MI][PG<BM, BN>::NJ])
{
    using G = PG<BM, BN>;
    const int t     = threadIdx.x;
    const int wbase = t & ~63;
    const int lane  = t & 63;
    const int col   = lane & 15;
    const int quad  = lane >> 4;
    const int w     = t >> 6;
    const int wrow  = (w >> 2) * (BM / 2);
    const int wcol  = (w & 3) * (BN / 4);
    const int NT    = K / G::BK;

    stage_tile<BM, BN>(A, Bt, m0, n0, K, 0, sL + 0 * G::SLOT, t, wbase);
    stage_tile<BM, BN>(A, Bt, m0, n0, K, 1, sL + 1 * G::SLOT, t, wbase);
    stage_tile<BM, BN>(A, Bt, m0, n0, K, 2, sL + 2 * G::SLOT, t, wbase);

    int T = 0;
#pragma unroll 1
    for (; T < NT - 3; ++T) {
        asm volatile("s_waitcnt vmcnt(%0)" :: "n"(2 * G::L) : "memory");
        __builtin_amdgcn_s_barrier();
        stage_tile<BM, BN>(A, Bt, m0, n0, K, T + 3, sL + ((T + 3) & 3) * G::SLOT, t, wbase);
        compute_tile<BM, BN>(sL + (T & 3) * G::SLOT, wrow, wcol, col, quad, acc);
    }
    asm volatile("s_waitcnt vmcnt(%0)" :: "n"(2 * G::L) : "memory");
    __builtin_amdgcn_s_barrier();
    compute_tile<BM, BN>(sL + (T & 3) * G::SLOT, wrow, wcol, col, quad, acc); ++T;
    asm volatile("s_waitcnt vmcnt(%0)" :: "n"(G::L) : "memory");
    __builtin_amdgcn_s_barrier();
    compute_tile<BM, BN>(sL + (T & 3) * G::SLOT, wrow, wcol, col, quad, acc); ++T;
    asm volatile("s_waitcnt vmcnt(0)" ::: "memory");
    __builtin_amdgcn_s_barrier();
    compute_tile<BM, BN>(sL + (T & 3) * G::SLOT, wrow, wcol, col, quad, acc);
}

// ---------------------------------------------------------------------------
// QKV GEMM: BM=128, BN=256 -> 32x12 = 384 blocks (was 192 at BM=256; 75%
// CU fill was the binding waste). acc[4][4]=64 VGPR, LDS 96 KiB.
// Fused RoPE/scale epilogue (proven R3-R6).
// ---------------------------------------------------------------------------
__global__ __launch_bounds__(512, 2) void gemm_qkv_kernel(
    const __bf16* __restrict__ xb, const __bf16* __restrict__ wT,
    const float* __restrict__ fc, const float* __restrict__ fs,
    __bf16* __restrict__ qb, __bf16* __restrict__ kb, __bf16* __restrict__ vb)
{
    __shared__ __bf16 sL[4 * PG<128, 256>::SLOT];   // 96 KiB
    f32x4 acc[4][4];
#pragma unroll
    for (int i = 0; i < 4; ++i)
#pragma unroll
        for (int j = 0; j < 4; ++j) acc[i][j] = (f32x4){0.f, 0.f, 0.f, 0.f};

    // T1: bijective XCD swizzle over 384 blocks (384 % 8 == 0).
    const int lin     = blockIdx.x;
    const int logical = (lin & 7) * 48 + (lin >> 3);
    const int bx      = logical % 12;          // 0-7 Q, 8-9 K, 10-11 V
    const int m0      = (logical / 12) * 128;
    const int n0      = bx * 256;

    gemm_pipe_body<128, 256>(xb, wT, m0, n0, E_, sL, acc);

    __bf16* Cp; int ldc, base;
    if (bx < 8)       { Cp = qb; ldc = H_ * D_;   base = 0;    }
    else if (bx < 10) { Cp = kb; ldc = HKV_ * D_; base = 2048; }
    else              { Cp = vb; ldc = HKV_ * D_; base = 2560; }
    const bool  doRope = (bx < 10);
    const float qsc    = (bx < 8) ? QK_SCALE_LOG2E : 1.0f;

    const int t    = threadIdx.x;
    const int lane = t & 63;
    const int col  = lane & 15;
    const int quad = lane >> 4;
    const int w    = t >> 6;
    const int wrow = (w >> 2) * 64;
    const int wcol = (w & 3) * 64;
#pragma unroll
    for (int i = 0; i < 4; ++i)
#pragma unroll
        for (int j = 0; j < 4; ++j)
#pragma unroll
            for (int r = 0; r < 4; ++r) {
                const int m  = m0 + wrow + i * 16 + quad * 4 + r;
                const int ng = n0 + wcol + j * 16 + col;
                float val = acc[i][j][r] * qsc;
                if (doRope) {
                    const int   s    = m & (S_ - 1);
                    const int   pair = (ng & 63) >> 1;
                    const float c    = fc[s * 32 + pair];
                    const float sn   = fs[s * 32 + pair];
                    const float oth  = __shfl_xor(val, 1);
                    val = (lane & 1) ? (oth * sn + val * c)
                                     : (val * c - oth * sn);
                }
                Cp[(size_t)m * ldc + (ng - base)] = (__bf16)val;
            }
}

// ---------------------------------------------------------------------------
// Output GEMM (BM=256, BN=128): 256 blocks (100% fill), bias epilogue.
// ---------------------------------------------------------------------------
__global__ __launch_bounds__(512, 2) void gemm_out_kernel(
    const __bf16* __restrict__ ob, const __bf16* __restrict__ woT,
    const float* __restrict__ bias, float* __restrict__ out)
{
    __shared__ __bf16 sL[4 * PG<256, 128>::SLOT];   // 96 KiB
    f32x4 acc[8][2];
#pragma unroll
    for (int i = 0; i < 8; ++i)
#pragma unroll
        for (int j = 0; j < 2; ++j) acc[i][j] = (f32x4){0.f, 0.f, 0.f, 0.f};

    const int lin     = blockIdx.x;
    const int logical = (lin & 7) * 32 + (lin >> 3);
    const int n0      = (logical % 16) * 128;
    const int m0      = (logical / 16) * 256;

    gemm_pipe_body<256, 128>(ob, woT, m0, n0, H_ * D_, sL, acc);

    const int t    = threadIdx.x;
    const int lane = t & 63;
    const int col  = lane & 15;
    const int quad = lane >> 4;
    const int w    = t >> 6;
    const int wrow = (w >> 2) * 128;
    const int wcol = (w & 3) * 32;
#pragma unroll
    for (int i = 0; i < 8; ++i)
#pragma unroll
        for (int j = 0; j < 2; ++j)
#pragma unroll
            for (int r = 0; r < 4; ++r) {
                const int m = m0 + wrow + i * 16 + quad * 4 + r;
                const int n = n0 + wcol + j * 16 + col;
                out[(size_t)m * E_ + n] = acc[i][j][r] + bias[n];
            }
}

// ---------------------------------------------------------------------------
// MFMA flash attention (R6 body verbatim: 112 µs, 116 VGPR, no spill).
// Dual-chain QK^T; V reads hoisted; exp2-direct; cvt_pk+permlane pack.
// __launch_bounds__(256) ONLY — forcing 4 waves/EU or 64q/wave spills
// 245-650 MB scratch (R3/R7/R8). ~180 VGPR+AGPR demand is structural.
// ---------------------------------------------------------------------------
struct StageRegs {
    bf16x8  k0, k1;
    ushort4 va0, vc0, va1, vc1;
};

__device__ __forceinline__ void stage_load(
    StageRegs& r, const __bf16* kbase, const __bf16* vbase, int j0,
    int kkey, int kd, int vkp, int vdg)
{
    const int KSTR = HKV_ * D_;   // 512
    const __bf16* kr = kbase + (size_t)(j0 + kkey) * KSTR + kd;
    r.k0 = ((const bf16x8*)kr)[0];
    r.k1 = ((const bf16x8*)kr)[1];
    const __bf16* v0 = vbase + (size_t)(j0 + vkp) * KSTR + vdg;
    r.va0 = *(const ushort4*)(v0);
    r.vc0 = *(const ushort4*)(v0 + KSTR);
    r.va1 = *(const ushort4*)(v0 + 32);
    r.vc1 = *(const ushort4*)(v0 + KSTR + 32);
}

__device__ __forceinline__ void stage_write(
    const StageRegs& r, __bf16 (*sK)[72], __bf16 (*sVT)[72],
    int kkey, int kd, int vkp, int vdg)
{
    *(bf16x8*)&sK[kkey][kd]     = r.k0;
    *(bf16x8*)&sK[kkey][kd + 8] = r.k1;
    *(unsigned int*)&sVT[vdg + 0][vkp]      = ((unsigned)r.vc0.x << 16) | r.va0.x;
    *(unsigned int*)&sVT[vdg + 1][vkp]      = ((unsigned)r.vc0.y << 16) | r.va0.y;
    *(unsigned int*)&sVT[vdg + 2][vkp]      = ((unsigned)r.vc0.z << 16) | r.va0.z;
    *(unsigned int*)&sVT[vdg + 3][vkp]      = ((unsigned)r.vc0.w << 16) | r.va0.w;
    *(unsigned int*)&sVT[vdg + 32 + 0][vkp] = ((unsigned)r.vc1.x << 16) | r.va1.x;
    *(unsigned int*)&sVT[vdg + 32 + 1][vkp] = ((unsigned)r.vc1.y << 16) | r.va1.y;
    *(unsigned int*)&sVT[vdg + 32 + 2][vkp] = ((unsigned)r.vc1.z << 16) | r.va1.z;
    *(unsigned int*)&sVT[vdg + 32 + 3][vkp] = ((unsigned)r.vc1.w << 16) | r.va1.w;
}

__device__ __forceinline__ bf16x8 pack_pa(const f32x16& p, int i0)
{
    unsigned a0, a1, a2, a3;
    asm("v_cvt_pk_bf16_f32 %0, %1, %2" : "=v"(a0) : "v"(p[i0 + 0]), "v"(p[i0 + 1]));
    asm("v_cvt_pk_bf16_f32 %0, %1, %2" : "=v"(a1) : "v"(p[i0 + 2]), "v"(p[i0 + 3]));
    asm("v_cvt_pk_bf16_f32 %0, %1, %2" : "=v"(a2) : "v"(p[i0 + 4]), "v"(p[i0 + 5]));
    asm("v_cvt_pk_bf16_f32 %0, %1, %2" : "=v"(a3) : "v"(p[i0 + 6]), "v"(p[i0 + 7]));
    const u32x2 s02 = __builtin_amdgcn_permlane32_swap(a0, a2, false, false);
    const u32x2 s13 = __builtin_amdgcn_permlane32_swap(a1, a3, false, false);
    return __builtin_bit_cast(bf16x8, (u32x4){s02[0], s13[0], s02[1], s13[1]});
}

__device__ __forceinline__ void attn_tile(
    const __bf16 (*sK)[72], const __bf16 (*sVT)[72],
    const bf16x8* bQ, int lq, int hi,
    f32x16& O0, f32x16& O1, float& lsum)
{
    f32x16 p0, p1;
#pragma unroll
    for (int i = 0; i < 16; ++i) { p0[i] = 0.f; p1[i] = 0.f; }
    __builtin_amdgcn_s_setprio(1);
#pragma unroll
    for (int ks = 0; ks < 4; ++ks) {
        const bf16x8 aK0 = *(const bf16x8*)&sK[lq][ks * 16 + hi * 8];
        const bf16x8 aK1 = *(const bf16x8*)&sK[32 + lq][ks * 16 + hi * 8];
        p0 = __builtin_amdgcn_mfma_f32_32x32x16_bf16(aK0, bQ[ks], p0, 0, 0, 0);
        p1 = __builtin_amdgcn_mfma_f32_32x32x16_bf16(aK1, bQ[ks], p1, 0, 0, 0);
    }
    __builtin_amdgcn_s_setprio(0);

    bf16x8 vbf[8];
#pragma unroll
    for (int ks = 0; ks < 4; ++ks) {
        vbf[ks * 2]     = *(const bf16x8*)&sVT[lq][ks * 16 + hi * 8];
        vbf[ks * 2 + 1] = *(const bf16x8*)&sVT[32 + lq][ks * 16 + hi * 8];
    }

    float ps = 0.f;
#pragma unroll
    for (int i = 0; i < 16; ++i) {
        p0[i] = __builtin_amdgcn_exp2f(p0[i]);
        p1[i] = __builtin_amdgcn_exp2f(p1[i]);
        ps += p0[i] + p1[i];
    }
    lsum += ps;

    bf16x8 pa[4];
    pa[0] = pack_pa(p0, 0);
    pa[1] = pack_pa(p0, 8);
    pa[2] = pack_pa(p1, 0);
    pa[3] = pack_pa(p1, 8);

    __builtin_amdgcn_s_setprio(1);
#pragma unroll
    for (int ks = 0; ks < 4; ++ks) {
        O0 = __builtin_amdgcn_mfma_f32_32x32x16_bf16(pa[ks], vbf[ks * 2],     O0, 0, 0, 0);
        O1 = __builtin_amdgcn_mfma_f32_32x32x16_bf16(pa[ks], vbf[ks * 2 + 1], O1, 0, 0, 0);
    }
    __builtin_amdgcn_s_setprio(0);
}

__global__ __launch_bounds__(256) void attn_kernel(
    const __bf16* __restrict__ qw, const __bf16* __restrict__ kw,
    const __bf16* __restrict__ vw, __bf16* __restrict__ ow)
{
    __shared__ __bf16 sK0[64][72], sVT0[64][72];
    __shared__ __bf16 sK1[64][72], sVT1[64][72];

    const int t    = threadIdx.x;
    const int lane = t & 63;
    const int w    = t >> 6;
    const int lq   = lane & 31;
    const int hi   = lane >> 5;

    const int bh  = blockIdx.y;
    const int b   = bh >> 5;
    const int h   = bh & 31;
    const int kvh = h >> 2;
    const int q0  = blockIdx.x * 128 + w * 32;

    bf16x8 bQ[4];
    {
        const __bf16* qrow = qw + (((size_t)b * S_ + q0 + lq) * H_ + h) * D_;
#pragma unroll
        for (int ks = 0; ks < 4; ++ks)
            bQ[ks] = *(const bf16x8*)(qrow + ks * 16 + hi * 8);
    }

    f32x16 O0, O1;
#pragma unroll
    for (int i = 0; i < 16; ++i) { O0[i] = 0.f; O1[i] = 0.f; }
    float lsum = 0.f;

    const __bf16* kbase = kw + ((size_t)b * S_ * HKV_ + kvh) * D_;
    const __bf16* vbase = vw + ((size_t)b * S_ * HKV_ + kvh) * D_;
    const int kkey = t >> 2,        kd  = (t & 3) * 16;
    const int vkp  = (t & 31) * 2,  vdg = (t >> 5) * 4;

    StageRegs sr;
    stage_load(sr, kbase, vbase, 0, kkey, kd, vkp, vdg);
    stage_write(sr, sK0, sVT0, kkey, kd, vkp, vdg);
    __syncthreads();

#pragma unroll 1
    for (int j0 = 0; j0 < S_; j0 += 128) {
        StageRegs nx;
        stage_load(nx, kbase, vbase, j0 + 64, kkey, kd, vkp, vdg);
        attn_tile(sK0, sVT0, bQ, lq, hi, O0, O1, lsum);
        stage_write(nx, sK1, sVT1, kkey, kd, vkp, vdg);
        __syncthreads();
        if (j0 + 128 < S_)
            stage_load(nx, kbase, vbase, j0 + 128, kkey, kd, vkp, vdg);
        attn_tile(sK1, sVT1, bQ, lq, hi, O0, O1, lsum);
        if (j0 + 128 < S_)
            stage_write(nx, sK0, sVT0, kkey, kd, vkp, vdg);
        __syncthreads();
    }

    lsum += __shfl_xor(lsum, 32);
    const float inv = 1.0f / lsum;

#pragma unroll
    for (int r = 0; r < 16; ++r) {
        const int   qr = (r & 3) + 8 * (r >> 2) + 4 * hi;
        const float li = __shfl(inv, qr);
        __bf16* orow = ow + (((size_t)b * S_ + q0 + qr) * H_ + h) * D_;
        orow[lq]      = (__bf16)(O0[r] * li);
        orow[32 + lq] = (__bf16)(O1[r] * li);
    }
}

// ---------------------------------------------------------------------------
extern "C" void kernel_launch(void* const* d_in, const int* in_sizes, int n_in,
                              void* d_out, int out_size, void* d_ws, size_t ws_size,
                              hipStream_t stream)
{
    const float* x  = (const float*)d_in[0];
    const float* fc = (const float*)d_in[2];
    const float* fs = (const float*)d_in[3];
    const float* wq = (const float*)d_in[4];
    const float* wk = (const float*)d_in[5];
    const float* wv = (const float*)d_in[6];
    const float* wo = (const float*)d_in[7];
    const float* obias = (const float*)d_in[8];
    float* out = (float*)d_out;

    __bf16* ws  = (__bf16*)d_ws;
    __bf16* xb  = ws;                                    // 4096*2048
    __bf16* wT  = xb  + (size_t)4096 * 2048;             // 3072*2048 [wq^T|wk^T|wv^T]
    __bf16* woT = wT  + (size_t)3072 * 2048;             // 2048*2048
    __bf16* qb  = woT + (size_t)2048 * 2048;             // B,S,H,D
    __bf16* kb  = qb  + (size_t)B_ * S_ * H_ * D_;       // B,S,HKV,D
    __bf16* vb  = kb  + (size_t)B_ * S_ * HKV_ * D_;
    __bf16* obf = vb  + (size_t)B_ * S_ * HKV_ * D_;     // B,S,H,D

    convert_kernel<<<4096, 256, 0, stream>>>(x, xb, 4096 * 2048 / 8);
    transpose_convert_all_kernel<<<dim3(160, 64), 256, 0, stream>>>(
        wq, wk, wv, wo, wT, woT);

    gemm_qkv_kernel<<<384, 512, 0, stream>>>(xb, wT, fc, fs, qb, kb, vb);

    attn_kernel<<<dim3(S_ / 128, B_ * H_), 256, 0, stream>>>(qb, kb, vb, obf);

    gemm_out_kernel<<<256, 512, 0, stream>>>(obf, woT, obias, out);
}

// Round 11
// 347.500 us; speedup vs baseline: 1.7806x; 1.0404x over previous
//
#include <hip/hip_runtime.h>
#include <math.h>

#define B_    2
#define S_    2048
#define E_    2048
#define H_    32
#define HKV_  8
#define D_    64

typedef __bf16 bf16x8 __attribute__((ext_vector_type(8)));
typedef float  f32x4  __attribute__((ext_vector_type(4)));
typedef float  f32x16 __attribute__((ext_vector_type(16)));
typedef unsigned int u32x2 __attribute__((ext_vector_type(2)));
typedef unsigned int u32x4 __attribute__((ext_vector_type(4)));

#define GPTR(x) ((const __attribute__((address_space(1))) void*)(x))
#define LPTR(x) ((__attribute__((address_space(3))) void*)(x))

// 0.125 * log2(e): folded into Q so attention softmax is exp2-direct.
#define QK_SCALE_LOG2E 0.18033688011112042f

// ---------------------------------------------------------------------------
// fp32 -> bf16 flat convert (x)
// ---------------------------------------------------------------------------
__global__ __launch_bounds__(256) void convert_kernel(
    const float* __restrict__ in, __bf16* __restrict__ out, int n8)
{
    const int i = blockIdx.x * 256 + threadIdx.x;
    if (i >= n8) return;
    const float4 a = ((const float4*)in)[i * 2];
    const float4 b = ((const float4*)in)[i * 2 + 1];
    bf16x8 o;
    o[0] = (__bf16)a.x; o[1] = (__bf16)a.y; o[2] = (__bf16)a.z; o[3] = (__bf16)a.w;
    o[4] = (__bf16)b.x; o[5] = (__bf16)b.y; o[6] = (__bf16)b.z; o[7] = (__bf16)b.w;
    ((bf16x8*)out)[i] = o;
}

// ---------------------------------------------------------------------------
// All 4 weight transposes (fp32 (K,N) -> bf16 (N,K)) in ONE dispatch.
// ---------------------------------------------------------------------------
__global__ __launch_bounds__(256) void transpose_convert_all_kernel(
    const float* __restrict__ wq, const float* __restrict__ wk,
    const float* __restrict__ wv, const float* __restrict__ wo,
    __bf16* __restrict__ wT, __bf16* __restrict__ woT)
{
    const float* in; __bf16* out; int N, xb;
    const int x = blockIdx.x;
    if (x < 64)      { in = wq; out = wT;                        N = 2048; xb = x; }
    else if (x < 80) { in = wk; out = wT + (size_t)2048 * 2048;  N = 512;  xb = x - 64; }
    else if (x < 96) { in = wv; out = wT + (size_t)2560 * 2048;  N = 512;  xb = x - 80; }
    else             { in = wo; out = woT;                       N = 2048; xb = x - 96; }
    const int K = 2048;

    __shared__ float tile[32][33];
    const int k0 = blockIdx.y * 32, n0 = xb * 32;
    const int r  = threadIdx.x >> 3;
    const int c4 = (threadIdx.x & 7) * 4;
    const float4 v = *(const float4*)&in[(size_t)(k0 + r) * N + n0 + c4];
    tile[r][c4 + 0] = v.x; tile[r][c4 + 1] = v.y;
    tile[r][c4 + 2] = v.z; tile[r][c4 + 3] = v.w;
    __syncthreads();
    ushort4 o;
    __bf16 h0 = (__bf16)tile[c4 + 0][r]; o.x = __builtin_bit_cast(unsigned short, h0);
    __bf16 h1 = (__bf16)tile[c4 + 1][r]; o.y = __builtin_bit_cast(unsigned short, h1);
    __bf16 h2 = (__bf16)tile[c4 + 2][r]; o.z = __builtin_bit_cast(unsigned short, h2);
    __bf16 h3 = (__bf16)tile[c4 + 3][r]; o.w = __builtin_bit_cast(unsigned short, h3);
    *(ushort4*)&out[(size_t)(n0 + r) * K + k0 + c4] = o;
}

// ---------------------------------------------------------------------------
// T3-minimum double-buffered GEMM (catalog recipe, measured 655-682 TF):
// BK=64, 2 LDS slots, 512 thr = 8 waves (2M x 4N). Per K-tile:
//   { stage(T+1 -> other slot); compute(T); vmcnt(0); barrier }
// ONE barrier per 64-K tile; loads get the whole 64-MFMA compute phase to
// land. Slot safety: stage(T+1) writes the slot whose readers finished
// before the PREVIOUS barrier (catalog-verified). LDS swizzle: 16B chunk
// c ^= (row&7) on both the pre-swizzled global source (gload_lds dest is
// linear base+lane*16B) and the ds_read index — m97-proven conflict-free.
// R9 lesson: the 8-phase schedule is a co-designed artifact; a near-port
// regresses. R10 lesson: BM=128 halves MFMA-per-barrier and loses more
// than fill gains. BK=32 ring: half the compute-per-sync of this.
// ---------------------------------------------------------------------------
template<int BM, int BN> struct DB {
    static constexpr int ASLOT = BM * 64;
    static constexpr int BSLOT = BN * 64;
    static constexpr int SLOT  = ASLOT + BSLOT;
    static constexpr int AG    = BM / 64;     // A stage instrs (64 rows each)
    static constexpr int BG    = BN / 64;
    static constexpr int MI    = BM / 32;     // A frags per wave
    static constexpr int NJ    = BN / 64;     // B frags per wave
};

template<int BM, int BN>
__device__ __forceinline__ void stage64(
    const __bf16* __restrict__ A, const __bf16* __restrict__ Bt,
    int m0, int n0, int K, int T, __bf16* sl, int t)
{
    using G = DB<BM, BN>;
    const int k0 = T * 64;
    const int rs = t >> 3;       // 0..63 row-in-group
    const int cp = t & 7;        // physical 16B chunk within 128B row
#pragma unroll
    for (int g = 0; g < G::AG; ++g) {
        const int row = g * 64 + rs;
        const int cs  = cp ^ (row & 7);          // pre-swizzled source chunk
        __builtin_amdgcn_global_load_lds(
            GPTR(A + (size_t)(m0 + row) * K + k0 + cs * 8),
            LPTR(sl + g * 4096 + t * 8), 16, 0, 0);
    }
#pragma unroll
    for (int g = 0; g < G::BG; ++g) {
        const int row = g * 64 + rs;
        const int cs  = cp ^ (row & 7);
        __builtin_amdgcn_global_load_lds(
            GPTR(Bt + (size_t)(n0 + row) * K + k0 + cs * 8),
            LPTR(sl + G::ASLOT + g * 4096 + t * 8), 16, 0, 0);
    }
}

template<int BM, int BN>
__device__ __forceinline__ void compute64(
    const __bf16* sl, int wrow, int wcol, int col, int quad,
    f32x4 acc[DB<BM, BN>::MI][DB<BM, BN>::NJ])
{
    using G = DB<BM, BN>;
#pragma unroll
    for (int kk = 0; kk < 2; ++kk) {
        bf16x8 af[G::MI], bfr[G::NJ];
#pragma unroll
        for (int i = 0; i < G::MI; ++i) {
            const int m = wrow + i * 16 + col;
            af[i] = *(const bf16x8*)&sl[m * 64 + (((kk * 4 + quad) ^ (m & 7)) * 8)];
        }
#pragma unroll
        for (int j = 0; j < G::NJ; ++j) {
            const int n = wcol + j * 16 + col;
            bfr[j] = *(const bf16x8*)&sl[G::ASLOT + n * 64 + (((kk * 4 + quad) ^ (n & 7)) * 8)];
        }
        __builtin_amdgcn_s_setprio(1);
#pragma unroll
        for (int i = 0; i < G::MI; ++i)
#pragma unroll
            for (int j = 0; j < G::NJ; ++j)
                acc[i][j] = __builtin_amdgcn_mfma_f32_16x16x32_bf16(
                    af[i], bfr[j], acc[i][j], 0, 0, 0);
        __builtin_amdgcn_s_setprio(0);
    }
}

template<int BM, int BN>
__device__ __forceinline__ void gemm_db_body(
    const __bf16* __restrict__ A, const __bf16* __restrict__ Bt,
    int m0, int n0, int K, __bf16* sL,
    f32x4 acc[DB<BM, BN>::MI][DB<BM, BN>::NJ])
{
    using G = DB<BM, BN>;
    const int t    = threadIdx.x;
    const int lane = t & 63;
    const int col  = lane & 15;
    const int quad = lane >> 4;
    const int w    = t >> 6;
    const int wrow = (w >> 2) * (BM / 2);
    const int wcol = (w & 3) * (BN / 4);
    const int NT   = K / 64;

    stage64<BM, BN>(A, Bt, m0, n0, K, 0, sL, t);
    asm volatile("s_waitcnt vmcnt(0)" ::: "memory");
    __builtin_amdgcn_s_barrier();

#pragma unroll 1
    for (int T = 0; T < NT; ++T) {
        if (T + 1 < NT)
            stage64<BM, BN>(A, Bt, m0, n0, K, T + 1, sL + ((T + 1) & 1) * G::SLOT, t);
        compute64<BM, BN>(sL + (T & 1) * G::SLOT, wrow, wcol, col, quad, acc);
        asm volatile("s_waitcnt vmcnt(0)" ::: "memory");
        __builtin_amdgcn_s_barrier();
    }
}

// ---------------------------------------------------------------------------
// QKV GEMM: BM=256, BN=192 -> 16x16 = 256 blocks = EXACTLY 100% CU fill
// (256-tile N-split was 192 blocks = 75%). Q/K/V split + RoPE handled
// per-element in the epilogue (regions are 64-aligned; each 16-lane n-range
// is region-uniform so shfl_xor stays wave-safe). LDS 112 KiB, acc[8][3].
// ---------------------------------------------------------------------------
__global__ __launch_bounds__(512, 2) void gemm_qkv_kernel(
    const __bf16* __restrict__ xb, const __bf16* __restrict__ wT,
    const float* __restrict__ fc, const float* __restrict__ fs,
    __bf16* __restrict__ qb, __bf16* __restrict__ kb, __bf16* __restrict__ vb)
{
    __shared__ __bf16 sL[2 * DB<256, 192>::SLOT];   // 112 KiB
    f32x4 acc[8][3];
#pragma unroll
    for (int i = 0; i < 8; ++i)
#pragma unroll
        for (int j = 0; j < 3; ++j) acc[i][j] = (f32x4){0.f, 0.f, 0.f, 0.f};

    // T1: bijective XCD swizzle over 256 blocks.
    const int lin     = blockIdx.x;
    const int logical = (lin & 7) * 32 + (lin >> 3);
    const int m0      = (logical >> 4) * 256;
    const int n0      = (logical & 15) * 192;

    gemm_db_body<256, 192>(xb, wT, m0, n0, E_, sL, acc);

    const int t    = threadIdx.x;
    const int lane = t & 63;
    const int col  = lane & 15;
    const int quad = lane >> 4;
    const int w    = t >> 6;
    const int wrow = (w >> 2) * 128;
    const int wcol = (w & 3) * 48;
#pragma unroll
    for (int i = 0; i < 8; ++i)
#pragma unroll
        for (int j = 0; j < 3; ++j)
#pragma unroll
            for (int r = 0; r < 4; ++r) {
                const int m = m0 + wrow + i * 16 + quad * 4 + r;
                const int n = n0 + wcol + j * 16 + col;   // 0..3071 global col
                float val = acc[i][j][r];
                if (n < 2560) {                            // Q or K: rope
                    if (n < 2048) val *= QK_SCALE_LOG2E;   // Q: fold scale
                    const int   s    = m & (S_ - 1);
                    const int   pair = (n & 63) >> 1;
                    const float c    = fc[s * 32 + pair];
                    const float sn   = fs[s * 32 + pair];
                    const float oth  = __shfl_xor(val, 1);
                    val = (lane & 1) ? (oth * sn + val * c)
                                     : (val * c - oth * sn);
                }
                if (n < 2048)
                    qb[(size_t)m * (H_ * D_) + n] = (__bf16)val;
                else if (n < 2560)
                    kb[(size_t)m * (HKV_ * D_) + (n - 2048)] = (__bf16)val;
                else
                    vb[(size_t)m * (HKV_ * D_) + (n - 2560)] = (__bf16)val;
            }
}

// ---------------------------------------------------------------------------
// Output GEMM: BM=256, BN=128 -> 16x16 = 256 blocks (100% fill), bias.
// ---------------------------------------------------------------------------
__global__ __launch_bounds__(512, 2) void gemm_out_kernel(
    const __bf16* __restrict__ ob, const __bf16* __restrict__ woT,
    const float* __restrict__ bias, float* __restrict__ out)
{
    __shared__ __bf16 sL[2 * DB<256, 128>::SLOT];   // 96 KiB
    f32x4 acc[8][2];
#pragma unroll
    for (int i = 0; i < 8; ++i)
#pragma unroll
        for (int j = 0; j < 2; ++j) acc[i][j] = (f32x4){0.f, 0.f, 0.f, 0.f};

    const int lin     = blockIdx.x;
    const int logical = (lin & 7) * 32 + (lin >> 3);
    const int n0      = (logical % 16) * 128;
    const int m0      = (logical / 16) * 256;

    gemm_db_body<256, 128>(ob, woT, m0, n0, H_ * D_, sL, acc);

    const int t    = threadIdx.x;
    const int lane = t & 63;
    const int col  = lane & 15;
    const int quad = lane >> 4;
    const int w    = t >> 6;
    const int wrow = (w >> 2) * 128;
    const int wcol = (w & 3) * 32;
#pragma unroll
    for (int i = 0; i < 8; ++i)
#pragma unroll
        for (int j = 0; j < 2; ++j)
#pragma unroll
            for (int r = 0; r < 4; ++r) {
                const int m = m0 + wrow + i * 16 + quad * 4 + r;
                const int n = n0 + wcol + j * 16 + col;
                out[(size_t)m * E_ + n] = acc[i][j][r] + bias[n];
            }
}

// ---------------------------------------------------------------------------
// MFMA flash attention (R6 body: ~108 µs, 116 VGPR, no spill).
// Dual-chain QK^T; V reads hoisted; exp2-direct; cvt_pk+permlane pack.
// __launch_bounds__(256) ONLY — forcing 4 waves/EU or 64q/wave spills
// 245-650 MB scratch (R3/R7/R8). ~180 VGPR+AGPR demand is structural.
// ---------------------------------------------------------------------------
struct StageRegs {
    bf16x8  k0, k1;
    ushort4 va0, vc0, va1, vc1;
};

__device__ __forceinline__ void stage_load(
    StageRegs& r, const __bf16* kbase, const __bf16* vbase, int j0,
    int kkey, int kd, int vkp, int vdg)
{
    const int KSTR = HKV_ * D_;   // 512
    const __bf16* kr = kbase + (size_t)(j0 + kkey) * KSTR + kd;
    r.k0 = ((const bf16x8*)kr)[0];
    r.k1 = ((const bf16x8*)kr)[1];
    const __bf16* v0 = vbase + (size_t)(j0 + vkp) * KSTR + vdg;
    r.va0 = *(const ushort4*)(v0);
    r.vc0 = *(const ushort4*)(v0 + KSTR);
    r.va1 = *(const ushort4*)(v0 + 32);
    r.vc1 = *(const ushort4*)(v0 + KSTR + 32);
}

__device__ __forceinline__ void stage_write(
    const StageRegs& r, __bf16 (*sK)[72], __bf16 (*sVT)[72],
    int kkey, int kd, int vkp, int vdg)
{
    *(bf16x8*)&sK[kkey][kd]     = r.k0;
    *(bf16x8*)&sK[kkey][kd + 8] = r.k1;
    *(unsigned int*)&sVT[vdg + 0][vkp]      = ((unsigned)r.vc0.x << 16) | r.va0.x;
    *(unsigned int*)&sVT[vdg + 1][vkp]      = ((unsigned)r.vc0.y << 16) | r.va0.y;
    *(unsigned int*)&sVT[vdg + 2][vkp]      = ((unsigned)r.vc0.z << 16) | r.va0.z;
    *(unsigned int*)&sVT[vdg + 3][vkp]      = ((unsigned)r.vc0.w << 16) | r.va0.w;
    *(unsigned int*)&sVT[vdg + 32 + 0][vkp] = ((unsigned)r.vc1.x << 16) | r.va1.x;
    *(unsigned int*)&sVT[vdg + 32 + 1][vkp] = ((unsigned)r.vc1.y << 16) | r.va1.y;
    *(unsigned int*)&sVT[vdg + 32 + 2][vkp] = ((unsigned)r.vc1.z << 16) | r.va1.z;
    *(unsigned int*)&sVT[vdg + 32 + 3][vkp] = ((unsigned)r.vc1.w << 16) | r.va1.w;
}

__device__ __forceinline__ bf16x8 pack_pa(const f32x16& p, int i0)
{
    unsigned a0, a1, a2, a3;
    asm("v_cvt_pk_bf16_f32 %0, %1, %2" : "=v"(a0) : "v"(p[i0 + 0]), "v"(p[i0 + 1]));
    asm("v_cvt_pk_bf16_f32 %0, %1, %2" : "=v"(a1) : "v"(p[i0 + 2]), "v"(p[i0 + 3]));
    asm("v_cvt_pk_bf16_f32 %0, %1, %2" : "=v"(a2) : "v"(p[i0 + 4]), "v"(p[i0 + 5]));
    asm("v_cvt_pk_bf16_f32 %0, %1, %2" : "=v"(a3) : "v"(p[i0 + 6]), "v"(p[i0 + 7]));
    const u32x2 s02 = __builtin_amdgcn_permlane32_swap(a0, a2, false, false);
    const u32x2 s13 = __builtin_amdgcn_permlane32_swap(a1, a3, false, false);
    return __builtin_bit_cast(bf16x8, (u32x4){s02[0], s13[0], s02[1], s13[1]});
}

__device__ __forceinline__ void attn_tile(
    const __bf16 (*sK)[72], const __bf16 (*sVT)[72],
    const bf16x8* bQ, int lq, int hi,
    f32x16& O0, f32x16& O1, float& lsum)
{
    f32x16 p0, p1;
#pragma unroll
    for (int i = 0; i < 16; ++i) { p0[i] = 0.f; p1[i] = 0.f; }
    __builtin_amdgcn_s_setprio(1);
#pragma unroll
    for (int ks = 0; ks < 4; ++ks) {
        const bf16x8 aK0 = *(const bf16x8*)&sK[lq][ks * 16 + hi * 8];
        const bf16x8 aK1 = *(const bf16x8*)&sK[32 + lq][ks * 16 + hi * 8];
        p0 = __builtin_amdgcn_mfma_f32_32x32x16_bf16(aK0, bQ[ks], p0, 0, 0, 0);
        p1 = __builtin_amdgcn_mfma_f32_32x32x16_bf16(aK1, bQ[ks], p1, 0, 0, 0);
    }
    __builtin_amdgcn_s_setprio(0);

    bf16x8 vbf[8];
#pragma unroll
    for (int ks = 0; ks < 4; ++ks) {
        vbf[ks * 2]     = *(const bf16x8*)&sVT[lq][ks * 16 + hi * 8];
        vbf[ks * 2 + 1] = *(const bf16x8*)&sVT[32 + lq][ks * 16 + hi * 8];
    }

    float ps = 0.f;
#pragma unroll
    for (int i = 0; i < 16; ++i) {
        p0[i] = __builtin_amdgcn_exp2f(p0[i]);
        p1[i] = __builtin_amdgcn_exp2f(p1[i]);
        ps += p0[i] + p1[i];
    }
    lsum += ps;

    bf16x8 pa[4];
    pa[0] = pack_pa(p0, 0);
    pa[1] = pack_pa(p0, 8);
    pa[2] = pack_pa(p1, 0);
    pa[3] = pack_pa(p1, 8);

    __builtin_amdgcn_s_setprio(1);
#pragma unroll
    for (int ks = 0; ks < 4; ++ks) {
        O0 = __builtin_amdgcn_mfma_f32_32x32x16_bf16(pa[ks], vbf[ks * 2],     O0, 0, 0, 0);
        O1 = __builtin_amdgcn_mfma_f32_32x32x16_bf16(pa[ks], vbf[ks * 2 + 1], O1, 0, 0, 0);
    }
    __builtin_amdgcn_s_setprio(0);
}

__global__ __launch_bounds__(256) void attn_kernel(
    const __bf16* __restrict__ qw, const __bf16* __restrict__ kw,
    const __bf16* __restrict__ vw, __bf16* __restrict__ ow)
{
    __shared__ __bf16 sK0[64][72], sVT0[64][72];
    __shared__ __bf16 sK1[64][72], sVT1[64][72];

    const int t    = threadIdx.x;
    const int lane = t & 63;
    const int w    = t >> 6;
    const int lq   = lane & 31;
    const int hi   = lane >> 5;

    const int bh  = blockIdx.y;
    const int b   = bh >> 5;
    const int h   = bh & 31;
    const int kvh = h >> 2;
    const int q0  = blockIdx.x * 128 + w * 32;

    bf16x8 bQ[4];
    {
        const __bf16* qrow = qw + (((size_t)b * S_ + q0 + lq) * H_ + h) * D_;
#pragma unroll
        for (int ks = 0; ks < 4; ++ks)
            bQ[ks] = *(const bf16x8*)(qrow + ks * 16 + hi * 8);
    }

    f32x16 O0, O1;
#pragma unroll
    for (int i = 0; i < 16; ++i) { O0[i] = 0.f; O1[i] = 0.f; }
    float lsum = 0.f;

    const __bf16* kbase = kw + ((size_t)b * S_ * HKV_ + kvh) * D_;
    const __bf16* vbase = vw + ((size_t)b * S_ * HKV_ + kvh) * D_;
    const int kkey = t >> 2,        kd  = (t & 3) * 16;
    const int vkp  = (t & 31) * 2,  vdg = (t >> 5) * 4;

    StageRegs sr;
    stage_load(sr, kbase, vbase, 0, kkey, kd, vkp, vdg);
    stage_write(sr, sK0, sVT0, kkey, kd, vkp, vdg);
    __syncthreads();

#pragma unroll 1
    for (int j0 = 0; j0 < S_; j0 += 128) {
        StageRegs nx;
        stage_load(nx, kbase, vbase, j0 + 64, kkey, kd, vkp, vdg);
        attn_tile(sK0, sVT0, bQ, lq, hi, O0, O1, lsum);
        stage_write(nx, sK1, sVT1, kkey, kd, vkp, vdg);
        __syncthreads();
        if (j0 + 128 < S_)
            stage_load(nx, kbase, vbase, j0 + 128, kkey, kd, vkp, vdg);
        attn_tile(sK1, sVT1, bQ, lq, hi, O0, O1, lsum);
        if (j0 + 128 < S_)
            stage_write(nx, sK0, sVT0, kkey, kd, vkp, vdg);
        __syncthreads();
    }

    lsum += __shfl_xor(lsum, 32);
    const float inv = 1.0f / lsum;

#pragma unroll
    for (int r = 0; r < 16; ++r) {
        const int   qr = (r & 3) + 8 * (r >> 2) + 4 * hi;
        const float li = __shfl(inv, qr);
        __bf16* orow = ow + (((size_t)b * S_ + q0 + qr) * H_ + h) * D_;
        orow[lq]      = (__bf16)(O0[r] * li);
        orow[32 + lq] = (__bf16)(O1[r] * li);
    }
}

// ---------------------------------------------------------------------------
extern "C" void kernel_launch(void* const* d_in, const int* in_sizes, int n_in,
                              void* d_out, int out_size, void* d_ws, size_t ws_size,
                              hipStream_t stream)
{
    const float* x  = (const float*)d_in[0];
    const float* fc = (const float*)d_in[2];
    const float* fs = (const float*)d_in[3];
    const float* wq = (const float*)d_in[4];
    const float* wk = (const float*)d_in[5];
    const float* wv = (const float*)d_in[6];
    const float* wo = (const float*)d_in[7];
    const float* obias = (const float*)d_in[8];
    float* out = (float*)d_out;

    __bf16* ws  = (__bf16*)d_ws;
    __bf16* xb  = ws;                                    // 4096*2048
    __bf16* wT  = xb  + (size_t)4096 * 2048;             // 3072*2048 [wq^T|wk^T|wv^T]
    __bf16* woT = wT  + (size_t)3072 * 2048;             // 2048*2048
    __bf16* qb  = woT + (size_t)2048 * 2048;             // B,S,H,D
    __bf16* kb  = qb  + (size_t)B_ * S_ * H_ * D_;       // B,S,HKV,D
    __bf16* vb  = kb  + (size_t)B_ * S_ * HKV_ * D_;
    __bf16* obf = vb  + (size_t)B_ * S_ * HKV_ * D_;     // B,S,H,D

    convert_kernel<<<4096, 256, 0, stream>>>(x, xb, 4096 * 2048 / 8);
    transpose_convert_all_kernel<<<dim3(160, 64), 256, 0, stream>>>(
        wq, wk, wv, wo, wT, woT);

    gemm_qkv_kernel<<<256, 512, 0, stream>>>(xb, wT, fc, fs, qb, kb, vb);

    attn_kernel<<<dim3(S_ / 128, B_ * H_), 256, 0, stream>>>(qb, kb, vb, obf);

    gemm_out_kernel<<<256, 512, 0, stream>>>(obf, woT, obias, out);
}

// Round 12
// 337.199 us; speedup vs baseline: 1.8350x; 1.0305x over previous
//
#include <hip/hip_runtime.h>
#include <math.h>

#define B_    2
#define S_    2048
#define E_    2048
#define H_    32
#define HKV_  8
#define D_    64

typedef __bf16 bf16x8 __attribute__((ext_vector_type(8)));
typedef float  f32x4  __attribute__((ext_vector_type(4)));
typedef float  f32x16 __attribute__((ext_vector_type(16)));
typedef unsigned int u32x2 __attribute__((ext_vector_type(2)));
typedef unsigned int u32x4 __attribute__((ext_vector_type(4)));

#define GPTR(x) ((const __attribute__((address_space(1))) void*)(x))
#define LPTR(x) ((__attribute__((address_space(3))) void*)(x))

// 0.125 * log2(e): folded into Q so attention softmax is exp2-direct.
#define QK_SCALE_LOG2E 0.18033688011112042f

// ---------------------------------------------------------------------------
// fp32 -> bf16 flat convert (x)
// ---------------------------------------------------------------------------
__global__ __launch_bounds__(256) void convert_kernel(
    const float* __restrict__ in, __bf16* __restrict__ out, int n8)
{
    const int i = blockIdx.x * 256 + threadIdx.x;
    if (i >= n8) return;
    const float4 a = ((const float4*)in)[i * 2];
    const float4 b = ((const float4*)in)[i * 2 + 1];
    bf16x8 o;
    o[0] = (__bf16)a.x; o[1] = (__bf16)a.y; o[2] = (__bf16)a.z; o[3] = (__bf16)a.w;
    o[4] = (__bf16)b.x; o[5] = (__bf16)b.y; o[6] = (__bf16)b.z; o[7] = (__bf16)b.w;
    ((bf16x8*)out)[i] = o;
}

// ---------------------------------------------------------------------------
// All 4 weight transposes (fp32 (K,N) -> bf16 (N,K)) in ONE dispatch.
// ---------------------------------------------------------------------------
__global__ __launch_bounds__(256) void transpose_convert_all_kernel(
    const float* __restrict__ wq, const float* __restrict__ wk,
    const float* __restrict__ wv, const float* __restrict__ wo,
    __bf16* __restrict__ wT, __bf16* __restrict__ woT)
{
    const float* in; __bf16* out; int N, xb;
    const int x = blockIdx.x;
    if (x < 64)      { in = wq; out = wT;                        N = 2048; xb = x; }
    else if (x < 80) { in = wk; out = wT + (size_t)2048 * 2048;  N = 512;  xb = x - 64; }
    else if (x < 96) { in = wv; out = wT + (size_t)2560 * 2048;  N = 512;  xb = x - 80; }
    else             { in = wo; out = woT;                       N = 2048; xb = x - 96; }
    const int K = 2048;

    __shared__ float tile[32][33];
    const int k0 = blockIdx.y * 32, n0 = xb * 32;
    const int r  = threadIdx.x >> 3;
    const int c4 = (threadIdx.x & 7) * 4;
    const float4 v = *(const float4*)&in[(size_t)(k0 + r) * N + n0 + c4];
    tile[r][c4 + 0] = v.x; tile[r][c4 + 1] = v.y;
    tile[r][c4 + 2] = v.z; tile[r][c4 + 3] = v.w;
    __syncthreads();
    ushort4 o;
    __bf16 h0 = (__bf16)tile[c4 + 0][r]; o.x = __builtin_bit_cast(unsigned short, h0);
    __bf16 h1 = (__bf16)tile[c4 + 1][r]; o.y = __builtin_bit_cast(unsigned short, h1);
    __bf16 h2 = (__bf16)tile[c4 + 2][r]; o.z = __builtin_bit_cast(unsigned short, h2);
    __bf16 h3 = (__bf16)tile[c4 + 3][r]; o.w = __builtin_bit_cast(unsigned short, h3);
    *(ushort4*)&out[(size_t)(n0 + r) * K + k0 + c4] = o;
}

// ---------------------------------------------------------------------------
// T3-minimum double-buffered GEMM (catalog recipe): BK=64, 2 LDS slots,
// 512 thr = 8 waves (2M x 4N). Per K-tile:
//   { stage(T+1 -> other slot); compute(T); vmcnt(0); barrier }
// R11 analysis: at 1 block/CU the vmcnt(0)+barrier drain has no other
// block to hide under (m233's 2-phase stall). R12: qkv shrinks BM to get
// LDS <= 80 KB -> 2 blocks/CU -> cross-block overlap of stage+drain.
// LDS swizzle: 16B chunk c ^= (row&7) both-sides (m97-proven).
// ---------------------------------------------------------------------------
template<int BM, int BN> struct DB {
    static constexpr int ASLOT = BM * 64;
    static constexpr int BSLOT = BN * 64;
    static constexpr int SLOT  = ASLOT + BSLOT;
    static constexpr int AG    = BM / 64;     // A stage instrs (64 rows each)
    static constexpr int BG    = BN / 64;
    static constexpr int MI    = BM / 32;     // A frags per wave
    static constexpr int NJ    = BN / 64;     // B frags per wave
};

template<int BM, int BN>
__device__ __forceinline__ void stage64(
    const __bf16* __restrict__ A, const __bf16* __restrict__ Bt,
    int m0, int n0, int K, int T, __bf16* sl, int t)
{
    using G = DB<BM, BN>;
    const int k0 = T * 64;
    const int rs = t >> 3;       // 0..63 row-in-group
    const int cp = t & 7;        // physical 16B chunk within 128B row
#pragma unroll
    for (int g = 0; g < G::AG; ++g) {
        const int row = g * 64 + rs;
        const int cs  = cp ^ (row & 7);          // pre-swizzled source chunk
        __builtin_amdgcn_global_load_lds(
            GPTR(A + (size_t)(m0 + row) * K + k0 + cs * 8),
            LPTR(sl + g * 4096 + t * 8), 16, 0, 0);
    }
#pragma unroll
    for (int g = 0; g < G::BG; ++g) {
        const int row = g * 64 + rs;
        const int cs  = cp ^ (row & 7);
        __builtin_amdgcn_global_load_lds(
            GPTR(Bt + (size_t)(n0 + row) * K + k0 + cs * 8),
            LPTR(sl + G::ASLOT + g * 4096 + t * 8), 16, 0, 0);
    }
}

template<int BM, int BN>
__device__ __forceinline__ void compute64(
    const __bf16* sl, int wrow, int wcol, int col, int quad,
    f32x4 acc[DB<BM, BN>::MI][DB<BM, BN>::NJ])
{
    using G = DB<BM, BN>;
#pragma unroll
    for (int kk = 0; kk < 2; ++kk) {
        bf16x8 af[G::MI], bfr[G::NJ];
#pragma unroll
        for (int i = 0; i < G::MI; ++i) {
            const int m = wrow + i * 16 + col;
            af[i] = *(const bf16x8*)&sl[m * 64 + (((kk * 4 + quad) ^ (m & 7)) * 8)];
        }
#pragma unroll
        for (int j = 0; j < G::NJ; ++j) {
            const int n = wcol + j * 16 + col;
            bfr[j] = *(const bf16x8*)&sl[G::ASLOT + n * 64 + (((kk * 4 + quad) ^ (n & 7)) * 8)];
        }
        __builtin_amdgcn_s_setprio(1);
#pragma unroll
        for (int i = 0; i < G::MI; ++i)
#pragma unroll
            for (int j = 0; j < G::NJ; ++j)
                acc[i][j] = __builtin_amdgcn_mfma_f32_16x16x32_bf16(
                    af[i], bfr[j], acc[i][j], 0, 0, 0);
        __builtin_amdgcn_s_setprio(0);
    }
}

template<int BM, int BN>
__device__ __forceinline__ void gemm_db_body(
    const __bf16* __restrict__ A, const __bf16* __restrict__ Bt,
    int m0, int n0, int K, __bf16* sL,
    f32x4 acc[DB<BM, BN>::MI][DB<BM, BN>::NJ])
{
    using G = DB<BM, BN>;
    const int t    = threadIdx.x;
    const int lane = t & 63;
    const int col  = lane & 15;
    const int quad = lane >> 4;
    const int w    = t >> 6;
    const int wrow = (w >> 2) * (BM / 2);
    const int wcol = (w & 3) * (BN / 4);
    const int NT   = K / 64;

    stage64<BM, BN>(A, Bt, m0, n0, K, 0, sL, t);
    asm volatile("s_waitcnt vmcnt(0)" ::: "memory");
    __builtin_amdgcn_s_barrier();

#pragma unroll 1
    for (int T = 0; T < NT; ++T) {
        if (T + 1 < NT)
            stage64<BM, BN>(A, Bt, m0, n0, K, T + 1, sL + ((T + 1) & 1) * G::SLOT, t);
        compute64<BM, BN>(sL + (T & 1) * G::SLOT, wrow, wcol, col, quad, acc);
        asm volatile("s_waitcnt vmcnt(0)" ::: "memory");
        __builtin_amdgcn_s_barrier();
    }
}

// ---------------------------------------------------------------------------
// QKV GEMM: BM=128, BN=192, BK=64 -> LDS 80 KiB -> 2 blocks/CU.
// Grid 32x16 = 512 blocks = exactly 2 full rounds (100% fill).
// Q/K/V split + RoPE per-element in epilogue (64-aligned regions;
// 16-lane n-ranges are region-uniform so shfl_xor stays wave-safe).
// ---------------------------------------------------------------------------
__global__ __launch_bounds__(512, 2) void gemm_qkv_kernel(
    const __bf16* __restrict__ xb, const __bf16* __restrict__ wT,
    const float* __restrict__ fc, const float* __restrict__ fs,
    __bf16* __restrict__ qb, __bf16* __restrict__ kb, __bf16* __restrict__ vb)
{
    __shared__ __bf16 sL[2 * DB<128, 192>::SLOT];   // 80 KiB
    f32x4 acc[4][3];
#pragma unroll
    for (int i = 0; i < 4; ++i)
#pragma unroll
        for (int j = 0; j < 3; ++j) acc[i][j] = (f32x4){0.f, 0.f, 0.f, 0.f};

    // T1: bijective XCD swizzle over 512 blocks (512 % 8 == 0).
    const int lin     = blockIdx.x;
    const int logical = (lin & 7) * 64 + (lin >> 3);
    const int m0      = (logical >> 4) * 128;
    const int n0      = (logical & 15) * 192;

    gemm_db_body<128, 192>(xb, wT, m0, n0, E_, sL, acc);

    const int t    = threadIdx.x;
    const int lane = t & 63;
    const int col  = lane & 15;
    const int quad = lane >> 4;
    const int w    = t >> 6;
    const int wrow = (w >> 2) * 64;
    const int wcol = (w & 3) * 48;
#pragma unroll
    for (int i = 0; i < 4; ++i)
#pragma unroll
        for (int j = 0; j < 3; ++j)
#pragma unroll
            for (int r = 0; r < 4; ++r) {
                const int m = m0 + wrow + i * 16 + quad * 4 + r;
                const int n = n0 + wcol + j * 16 + col;   // 0..3071 global col
                float val = acc[i][j][r];
                if (n < 2560) {                            // Q or K: rope
                    if (n < 2048) val *= QK_SCALE_LOG2E;   // Q: fold scale
                    const int   s    = m & (S_ - 1);
                    const int   pair = (n & 63) >> 1;
                    const float c    = fc[s * 32 + pair];
                    const float sn   = fs[s * 32 + pair];
                    const float oth  = __shfl_xor(val, 1);
                    val = (lane & 1) ? (oth * sn + val * c)
                                     : (val * c - oth * sn);
                }
                if (n < 2048)
                    qb[(size_t)m * (H_ * D_) + n] = (__bf16)val;
                else if (n < 2560)
                    kb[(size_t)m * (HKV_ * D_) + (n - 2048)] = (__bf16)val;
                else
                    vb[(size_t)m * (HKV_ * D_) + (n - 2560)] = (__bf16)val;
            }
}

// ---------------------------------------------------------------------------
// Output GEMM: BM=256, BN=128 -> 16x16 = 256 blocks (100% fill), bias.
// (Unchanged from R11 to isolate the qkv change.)
// ---------------------------------------------------------------------------
__global__ __launch_bounds__(512, 2) void gemm_out_kernel(
    const __bf16* __restrict__ ob, const __bf16* __restrict__ woT,
    const float* __restrict__ bias, float* __restrict__ out)
{
    __shared__ __bf16 sL[2 * DB<256, 128>::SLOT];   // 96 KiB
    f32x4 acc[8][2];
#pragma unroll
    for (int i = 0; i < 8; ++i)
#pragma unroll
        for (int j = 0; j < 2; ++j) acc[i][j] = (f32x4){0.f, 0.f, 0.f, 0.f};

    const int lin     = blockIdx.x;
    const int logical = (lin & 7) * 32 + (lin >> 3);
    const int n0      = (logical % 16) * 128;
    const int m0      = (logical / 16) * 256;

    gemm_db_body<256, 128>(ob, woT, m0, n0, H_ * D_, sL, acc);

    const int t    = threadIdx.x;
    const int lane = t & 63;
    const int col  = lane & 15;
    const int quad = lane >> 4;
    const int w    = t >> 6;
    const int wrow = (w >> 2) * 128;
    const int wcol = (w & 3) * 32;
#pragma unroll
    for (int i = 0; i < 8; ++i)
#pragma unroll
        for (int j = 0; j < 2; ++j)
#pragma unroll
            for (int r = 0; r < 4; ++r) {
                const int m = m0 + wrow + i * 16 + quad * 4 + r;
                const int n = n0 + wcol + j * 16 + col;
                out[(size_t)m * E_ + n] = acc[i][j][r] + bias[n];
            }
}

// ---------------------------------------------------------------------------
// MFMA flash attention (R6 body: ~107 µs, 116 VGPR, no spill).
// Dual-chain QK^T; V reads hoisted; exp2-direct; cvt_pk+permlane pack.
// __launch_bounds__(256) ONLY — forcing 4 waves/EU or 64q/wave spills
// 245-650 MB scratch (R3/R7/R8). ~180 VGPR+AGPR demand is structural.
// ---------------------------------------------------------------------------
struct StageRegs {
    bf16x8  k0, k1;
    ushort4 va0, vc0, va1, vc1;
};

__device__ __forceinline__ void stage_load(
    StageRegs& r, const __bf16* kbase, const __bf16* vbase, int j0,
    int kkey, int kd, int vkp, int vdg)
{
    const int KSTR = HKV_ * D_;   // 512
    const __bf16* kr = kbase + (size_t)(j0 + kkey) * KSTR + kd;
    r.k0 = ((const bf16x8*)kr)[0];
    r.k1 = ((const bf16x8*)kr)[1];
    const __bf16* v0 = vbase + (size_t)(j0 + vkp) * KSTR + vdg;
    r.va0 = *(const ushort4*)(v0);
    r.vc0 = *(const ushort4*)(v0 + KSTR);
    r.va1 = *(const ushort4*)(v0 + 32);
    r.vc1 = *(const ushort4*)(v0 + KSTR + 32);
}

__device__ __forceinline__ void stage_write(
    const StageRegs& r, __bf16 (*sK)[72], __bf16 (*sVT)[72],
    int kkey, int kd, int vkp, int vdg)
{
    *(bf16x8*)&sK[kkey][kd]     = r.k0;
    *(bf16x8*)&sK[kkey][kd + 8] = r.k1;
    *(unsigned int*)&sVT[vdg + 0][vkp]      = ((unsigned)r.vc0.x << 16) | r.va0.x;
    *(unsigned int*)&sVT[vdg + 1][vkp]      = ((unsigned)r.vc0.y << 16) | r.va0.y;
    *(unsigned int*)&sVT[vdg + 2][vkp]      = ((unsigned)r.vc0.z << 16) | r.va0.z;
    *(unsigned int*)&sVT[vdg + 3][vkp]      = ((unsigned)r.vc0.w << 16) | r.va0.w;
    *(unsigned int*)&sVT[vdg + 32 + 0][vkp] = ((unsigned)r.vc1.x << 16) | r.va1.x;
    *(unsigned int*)&sVT[vdg + 32 + 1][vkp] = ((unsigned)r.vc1.y << 16) | r.va1.y;
    *(unsigned int*)&sVT[vdg + 32 + 2][vkp] = ((unsigned)r.vc1.z << 16) | r.va1.z;
    *(unsigned int*)&sVT[vdg + 32 + 3][vkp] = ((unsigned)r.vc1.w << 16) | r.va1.w;
}

__device__ __forceinline__ bf16x8 pack_pa(const f32x16& p, int i0)
{
    unsigned a0, a1, a2, a3;
    asm("v_cvt_pk_bf16_f32 %0, %1, %2" : "=v"(a0) : "v"(p[i0 + 0]), "v"(p[i0 + 1]));
    asm("v_cvt_pk_bf16_f32 %0, %1, %2" : "=v"(a1) : "v"(p[i0 + 2]), "v"(p[i0 + 3]));
    asm("v_cvt_pk_bf16_f32 %0, %1, %2" : "=v"(a2) : "v"(p[i0 + 4]), "v"(p[i0 + 5]));
    asm("v_cvt_pk_bf16_f32 %0, %1, %2" : "=v"(a3) : "v"(p[i0 + 6]), "v"(p[i0 + 7]));
    const u32x2 s02 = __builtin_amdgcn_permlane32_swap(a0, a2, false, false);
    const u32x2 s13 = __builtin_amdgcn_permlane32_swap(a1, a3, false, false);
    return __builtin_bit_cast(bf16x8, (u32x4){s02[0], s13[0], s02[1], s13[1]});
}

__device__ __forceinline__ void attn_tile(
    const __bf16 (*sK)[72], const __bf16 (*sVT)[72],
    const bf16x8* bQ, int lq, int hi,
    f32x16& O0, f32x16& O1, float& lsum)
{
    f32x16 p0, p1;
#pragma unroll
    for (int i = 0; i < 16; ++i) { p0[i] = 0.f; p1[i] = 0.f; }
    __builtin_amdgcn_s_setprio(1);
#pragma unroll
    for (int ks = 0; ks < 4; ++ks) {
        const bf16x8 aK0 = *(const bf16x8*)&sK[lq][ks * 16 + hi * 8];
        const bf16x8 aK1 = *(const bf16x8*)&sK[32 + lq][ks * 16 + hi * 8];
        p0 = __builtin_amdgcn_mfma_f32_32x32x16_bf16(aK0, bQ[ks], p0, 0, 0, 0);
        p1 = __builtin_amdgcn_mfma_f32_32x32x16_bf16(aK1, bQ[ks], p1, 0, 0, 0);
    }
    __builtin_amdgcn_s_setprio(0);

    bf16x8 vbf[8];
#pragma unroll
    for (int ks = 0; ks < 4; ++ks) {
        vbf[ks * 2]     = *(const bf16x8*)&sVT[lq][ks * 16 + hi * 8];
        vbf[ks * 2 + 1] = *(const bf16x8*)&sVT[32 + lq][ks * 16 + hi * 8];
    }

    float ps = 0.f;
#pragma unroll
    for (int i = 0; i < 16; ++i) {
        p0[i] = __builtin_amdgcn_exp2f(p0[i]);
        p1[i] = __builtin_amdgcn_exp2f(p1[i]);
        ps += p0[i] + p1[i];
    }
    lsum += ps;

    bf16x8 pa[4];
    pa[0] = pack_pa(p0, 0);
    pa[1] = pack_pa(p0, 8);
    pa[2] = pack_pa(p1, 0);
    pa[3] = pack_pa(p1, 8);

    __builtin_amdgcn_s_setprio(1);
#pragma unroll
    for (int ks = 0; ks < 4; ++ks) {
        O0 = __builtin_amdgcn_mfma_f32_32x32x16_bf16(pa[ks], vbf[ks * 2],     O0, 0, 0, 0);
        O1 = __builtin_amdgcn_mfma_f32_32x32x16_bf16(pa[ks], vbf[ks * 2 + 1], O1, 0, 0, 0);
    }
    __builtin_amdgcn_s_setprio(0);
}

__global__ __launch_bounds__(256) void attn_kernel(
    const __bf16* __restrict__ qw, const __bf16* __restrict__ kw,
    const __bf16* __restrict__ vw, __bf16* __restrict__ ow)
{
    __shared__ __bf16 sK0[64][72], sVT0[64][72];
    __shared__ __bf16 sK1[64][72], sVT1[64][72];

    const int t    = threadIdx.x;
    const int lane = t & 63;
    const int w    = t >> 6;
    const int lq   = lane & 31;
    const int hi   = lane >> 5;

    const int bh  = blockIdx.y;
    const int b   = bh >> 5;
    const int h   = bh & 31;
    const int kvh = h >> 2;
    const int q0  = blockIdx.x * 128 + w * 32;

    bf16x8 bQ[4];
    {
        const __bf16* qrow = qw + (((size_t)b * S_ + q0 + lq) * H_ + h) * D_;
#pragma unroll
        for (int ks = 0; ks < 4; ++ks)
            bQ[ks] = *(const bf16x8*)(qrow + ks * 16 + hi * 8);
    }

    f32x16 O0, O1;
#pragma unroll
    for (int i = 0; i < 16; ++i) { O0[i] = 0.f; O1[i] = 0.f; }
    float lsum = 0.f;

    const __bf16* kbase = kw + ((size_t)b * S_ * HKV_ + kvh) * D_;
    const __bf16* vbase = vw + ((size_t)b * S_ * HKV_ + kvh) * D_;
    const int kkey = t >> 2,        kd  = (t & 3) * 16;
    const int vkp  = (t & 31) * 2,  vdg = (t >> 5) * 4;

    StageRegs sr;
    stage_load(sr, kbase, vbase, 0, kkey, kd, vkp, vdg);
    stage_write(sr, sK0, sVT0, kkey, kd, vkp, vdg);
    __syncthreads();

#pragma unroll 1
    for (int j0 = 0; j0 < S_; j0 += 128) {
        StageRegs nx;
        stage_load(nx, kbase, vbase, j0 + 64, kkey, kd, vkp, vdg);
        attn_tile(sK0, sVT0, bQ, lq, hi, O0, O1, lsum);
        stage_write(nx, sK1, sVT1, kkey, kd, vkp, vdg);
        __syncthreads();
        if (j0 + 128 < S_)
            stage_load(nx, kbase, vbase, j0 + 128, kkey, kd, vkp, vdg);
        attn_tile(sK1, sVT1, bQ, lq, hi, O0, O1, lsum);
        if (j0 + 128 < S_)
            stage_write(nx, sK0, sVT0, kkey, kd, vkp, vdg);
        __syncthreads();
    }

    lsum += __shfl_xor(lsum, 32);
    const float inv = 1.0f / lsum;

#pragma unroll
    for (int r = 0; r < 16; ++r) {
        const int   qr = (r & 3) + 8 * (r >> 2) + 4 * hi;
        const float li = __shfl(inv, qr);
        __bf16* orow = ow + (((size_t)b * S_ + q0 + qr) * H_ + h) * D_;
        orow[lq]      = (__bf16)(O0[r] * li);
        orow[32 + lq] = (__bf16)(O1[r] * li);
    }
}

// ---------------------------------------------------------------------------
extern "C" void kernel_launch(void* const* d_in, const int* in_sizes, int n_in,
                              void* d_out, int out_size, void* d_ws, size_t ws_size,
                              hipStream_t stream)
{
    const float* x  = (const float*)d_in[0];
    const float* fc = (const float*)d_in[2];
    const float* fs = (const float*)d_in[3];
    const float* wq = (const float*)d_in[4];
    const float* wk = (const float*)d_in[5];
    const float* wv = (const float*)d_in[6];
    const float* wo = (const float*)d_in[7];
    const float* obias = (const float*)d_in[8];
    float* out = (float*)d_out;

    __bf16* ws  = (__bf16*)d_ws;
    __bf16* xb  = ws;                                    // 4096*2048
    __bf16* wT  = xb  + (size_t)4096 * 2048;             // 3072*2048 [wq^T|wk^T|wv^T]
    __bf16* woT = wT  + (size_t)3072 * 2048;             // 2048*2048
    __bf16* qb  = woT + (size_t)2048 * 2048;             // B,S,H,D
    __bf16* kb  = qb  + (size_t)B_ * S_ * H_ * D_;       // B,S,HKV,D
    __bf16* vb  = kb  + (size_t)B_ * S_ * HKV_ * D_;
    __bf16* obf = vb  + (size_t)B_ * S_ * HKV_ * D_;     // B,S,H,D

    convert_kernel<<<4096, 256, 0, stream>>>(x, xb, 4096 * 2048 / 8);
    transpose_convert_all_kernel<<<dim3(160, 64), 256, 0, stream>>>(
        wq, wk, wv, wo, wT, woT);

    gemm_qkv_kernel<<<512, 512, 0, stream>>>(xb, wT, fc, fs, qb, kb, vb);

    attn_kernel<<<dim3(S_ / 128, B_ * H_), 256, 0, stream>>>(qb, kb, vb, obf);

    gemm_out_kernel<<<256, 512, 0, stream>>>(obf, woT, obias, out);
}